// Round 1
// baseline (420.179 us; speedup 1.0000x reference)
//
#include <hip/hip_runtime.h>
#include <cstdint>

typedef __attribute__((ext_vector_type(8))) short bf16x8;
typedef __attribute__((ext_vector_type(4))) float f32x4;
typedef __attribute__((ext_vector_type(4))) unsigned short u16x4;
typedef unsigned short u16;

#define LOG2E 1.44269504088896340736f

__device__ __forceinline__ u16 f2bf(float f) {
  unsigned u = __builtin_bit_cast(unsigned, f);
  u += 0x7FFFu + ((u >> 16) & 1u);
  return (u16)(u >> 16);
}
__device__ __forceinline__ float bf2f(u16 h) {
  return __builtin_bit_cast(float, ((unsigned)h) << 16);
}

#define GLOAD_LDS16(g, l)                                                              \
  __builtin_amdgcn_global_load_lds((const __attribute__((address_space(1))) void*)(g), \
                                   (__attribute__((address_space(3))) void*)(l), 16, 0, 0)

// ---------------- weight transpose f32[K][N] -> bf16[N][K] ----------------
__global__ __launch_bounds__(256) void k_transpose_bf16(
    const float* __restrict__ W, u16* __restrict__ Wt, int K, int N) {
  __shared__ float tile[32][33];
  const int tid = threadIdx.x;
  const int tx = tid & 31, ty = tid >> 5;
  const int n0 = blockIdx.x * 32, k0 = blockIdx.y * 32;
#pragma unroll
  for (int i = 0; i < 32; i += 8)
    tile[ty + i][tx] = W[(size_t)(k0 + ty + i) * N + n0 + tx];
  __syncthreads();
#pragma unroll
  for (int i = 0; i < 32; i += 8)
    Wt[(size_t)(n0 + ty + i) * K + k0 + tx] = f2bf(tile[tx][ty + i]);
}

// ---------------- LayerNorm f32[row][1024] -> bf16 ----------------
__global__ __launch_bounds__(256) void k_layernorm_bf16(
    const float* __restrict__ x, const float* __restrict__ g,
    const float* __restrict__ b, u16* __restrict__ y) {
  const int row = blockIdx.x, tid = threadIdx.x;
  const float4 v = ((const float4*)(x + (size_t)row * 1024))[tid];
  float s = v.x + v.y + v.z + v.w;
#pragma unroll
  for (int m = 1; m < 64; m <<= 1) s += __shfl_xor(s, m);
  __shared__ float ps[8];
  if ((tid & 63) == 0) ps[tid >> 6] = s;
  __syncthreads();
  const float mean = (ps[0] + ps[1] + ps[2] + ps[3]) * (1.0f / 1024.0f);
  const float d0 = v.x - mean, d1 = v.y - mean, d2 = v.z - mean, d3 = v.w - mean;
  float s2 = d0 * d0 + d1 * d1 + d2 * d2 + d3 * d3;
#pragma unroll
  for (int m = 1; m < 64; m <<= 1) s2 += __shfl_xor(s2, m);
  if ((tid & 63) == 0) ps[4 + (tid >> 6)] = s2;
  __syncthreads();
  const float var = (ps[4] + ps[5] + ps[6] + ps[7]) * (1.0f / 1024.0f);
  const float rstd = rsqrtf(var + 1e-5f);
  const float4 gv = ((const float4*)g)[tid];
  const float4 bv = ((const float4*)b)[tid];
  u16x4 o;
  o[0] = f2bf(d0 * rstd * gv.x + bv.x);
  o[1] = f2bf(d1 * rstd * gv.y + bv.y);
  o[2] = f2bf(d2 * rstd * gv.z + bv.z);
  o[3] = f2bf(d3 * rstd * gv.w + bv.w);
  *(u16x4*)(y + (size_t)row * 1024 + tid * 4) = o;
}

__device__ __forceinline__ float gelu_f(float x) {
  const float u = 0.7978845608028654f * (x + 0.044715f * x * x * x);
  const float e = exp2f(u * 2.8853900817779268f);  // e^{2u}
  const float t = 1.0f - 2.0f / (e + 1.0f);        // tanh(u)
  return 0.5f * x * (1.0f + t);
}

// ---------------- GEMM: C[M,N] = A[M,K](bf16) * Bt[N,K]^T(bf16) + bias ----------------
// EPI 0: bf16 out         EPI 1: f32 out + bf16 residual        EPI 2: bf16 out + gelu
template <int EPI>
__global__ __launch_bounds__(256, 2) void k_gemm_bt(
    const u16* __restrict__ A, const u16* __restrict__ Bt,
    const float* __restrict__ bias, const u16* __restrict__ resid,
    void* __restrict__ out, int M, int N, int K) {
  __shared__ u16 As[128 * 64];
  __shared__ u16 Bs[128 * 64];
  const int tid = threadIdx.x;
  const int rowBase = blockIdx.y * 128, colBase = blockIdx.x * 128;
  const int w = tid >> 6, l = tid & 63;
  const int wm = w >> 1, wn = w & 1;
  const int lrow = l & 15, lg = l >> 4;
  const int srow = tid >> 3, sslot = tid & 7;

  const f32x4 fz = {0.f, 0.f, 0.f, 0.f};
  f32x4 acc[4][4];
#pragma unroll
  for (int m = 0; m < 4; m++)
#pragma unroll
    for (int n = 0; n < 4; n++) acc[m][n] = fz;

  for (int kt = 0; kt < K; kt += 64) {
#pragma unroll
    for (int i = 0; i < 4; i++) {
      const int r = srow + 32 * i;
      const int gs = sslot ^ (r & 7);  // inverse-swizzled source, linear LDS dest
      GLOAD_LDS16(A + (size_t)(rowBase + r) * K + kt + gs * 8, (char*)As + i * 4096 + tid * 16);
      GLOAD_LDS16(Bt + (size_t)(colBase + r) * K + kt + gs * 8, (char*)Bs + i * 4096 + tid * 16);
    }
    __syncthreads();
#pragma unroll
    for (int kc = 0; kc < 2; kc++) {
      bf16x8 av[4], bv[4];
#pragma unroll
      for (int m = 0; m < 4; m++) {
        const int r = wm * 64 + m * 16 + lrow;
        const int sl = (kc * 4 + lg) ^ (r & 7);
        av[m] = *(const bf16x8*)((const char*)As + r * 128 + sl * 16);
      }
#pragma unroll
      for (int n = 0; n < 4; n++) {
        const int r = wn * 64 + n * 16 + lrow;
        const int sl = (kc * 4 + lg) ^ (r & 7);
        bv[n] = *(const bf16x8*)((const char*)Bs + r * 128 + sl * 16);
      }
#pragma unroll
      for (int m = 0; m < 4; m++)
#pragma unroll
        for (int n = 0; n < 4; n++)
          acc[m][n] = __builtin_amdgcn_mfma_f32_16x16x32_bf16(av[m], bv[n], acc[m][n], 0, 0, 0);
    }
    __syncthreads();
  }
#pragma unroll
  for (int n = 0; n < 4; n++) {
    const int col = colBase + wn * 64 + n * 16 + lrow;
    const float bval = bias[col];
#pragma unroll
    for (int m = 0; m < 4; m++) {
      const int row0 = rowBase + wm * 64 + m * 16 + lg * 4;
#pragma unroll
      for (int r = 0; r < 4; r++) {
        const size_t idx = (size_t)(row0 + r) * N + col;
        float v = acc[m][n][r] + bval;
        if (EPI == 0) {
          ((u16*)out)[idx] = f2bf(v);
        } else if (EPI == 2) {
          ((u16*)out)[idx] = f2bf(gelu_f(v));
        } else {
          v += bf2f(resid[idx]);
          ((float*)out)[idx] = v;
        }
      }
    }
  }
}

// ---------------- causal flash attention ----------------
// qkv bf16 [B*S][3072] (q|k|v each 1024 = 16 heads * 64), out bf16 [B*S][1024]
__global__ __launch_bounds__(256, 2) void k_attention(
    const u16* __restrict__ qkv, u16* __restrict__ out) {
  const int S = 2048, E3 = 3072;
  const int qt = blockIdx.x, bh = blockIdx.y;
  const int bat = bh >> 4, h = bh & 15;
  const u16* base = qkv + (size_t)bat * S * E3;
  const int tid = threadIdx.x, w = tid >> 6, l = tid & 63;
  const int lrow = l & 15, lg = l >> 4;
  __shared__ u16 Ks[64 * 72];      // [key][d] padded stride 72
  __shared__ u16 Vt[64 * 72];      // [d][key] padded stride 72
  __shared__ u16 Pl[4][32 * 72];   // per-wave P, [q][key] padded
  u16* Plw = Pl[w];
  const int qrow0 = qt * 128 + w * 32;

  bf16x8 qfrag[2][2];
#pragma unroll
  for (int qi = 0; qi < 2; qi++)
#pragma unroll
    for (int kc = 0; kc < 2; kc++)
      qfrag[qi][kc] = *(const bf16x8*)(base + (size_t)(qrow0 + qi * 16 + lrow) * E3 + h * 64 + kc * 32 + lg * 8);

  const f32x4 fz = {0.f, 0.f, 0.f, 0.f};
  f32x4 o[2][4];
  float mrow[2][4], lsum[2][4];
#pragma unroll
  for (int qi = 0; qi < 2; qi++) {
#pragma unroll
    for (int r = 0; r < 4; r++) { mrow[qi][r] = -1e30f; lsum[qi][r] = 0.f; }
#pragma unroll
    for (int df = 0; df < 4; df++) o[qi][df] = fz;
  }

  const int nkt = 2 * qt + 2;
  const int kstg = tid >> 3, dstg = tid & 7;
  for (int kt = 0; kt < nkt; kt++) {
    const int kb = kt * 64;
    // stage K (row-major, padded) and V (transposed, rotated scatter)
#pragma unroll
    for (int p = 0; p < 2; p++) {
      const int kk = kstg + p * 32;
      const bf16x8 kv = *(const bf16x8*)(base + (size_t)(kb + kk) * E3 + 1024 + h * 64 + dstg * 8);
      *(bf16x8*)((char*)Ks + kk * 144 + dstg * 16) = kv;
      const bf16x8 vv = *(const bf16x8*)(base + (size_t)(kb + kk) * E3 + 2048 + h * 64 + dstg * 8);
#pragma unroll
      for (int jj = 0; jj < 8; jj++) {
        const int j = (jj + dstg) & 7;
        *((u16*)((char*)Vt + (dstg * 8 + j) * 144 + kk * 2)) = (u16)vv[j];
      }
    }
    __syncthreads();
    // S = Q K^T
    f32x4 sv[2][4];
#pragma unroll
    for (int qi = 0; qi < 2; qi++)
#pragma unroll
      for (int kf = 0; kf < 4; kf++) sv[qi][kf] = fz;
#pragma unroll
    for (int kc = 0; kc < 2; kc++) {
      bf16x8 kfr[4];
#pragma unroll
      for (int kf = 0; kf < 4; kf++)
        kfr[kf] = *(const bf16x8*)((char*)Ks + (kf * 16 + lrow) * 144 + kc * 64 + lg * 16);
#pragma unroll
      for (int qi = 0; qi < 2; qi++)
#pragma unroll
        for (int kf = 0; kf < 4; kf++)
          sv[qi][kf] = __builtin_amdgcn_mfma_f32_16x16x32_bf16(qfrag[qi][kc], kfr[kf], sv[qi][kf], 0, 0, 0);
    }
    // scale + causal mask (C-layout: row=lg*4+r, col=lrow)
#pragma unroll
    for (int qi = 0; qi < 2; qi++)
#pragma unroll
      for (int kf = 0; kf < 4; kf++) {
        const int kg = kb + kf * 16 + lrow;
#pragma unroll
        for (int r = 0; r < 4; r++) {
          const int qg = qrow0 + qi * 16 + lg * 4 + r;
          const float xv = sv[qi][kf][r] * 0.125f;
          sv[qi][kf][r] = (kg > qg) ? -1e30f : xv;
        }
      }
    // online softmax
#pragma unroll
    for (int qi = 0; qi < 2; qi++) {
#pragma unroll
      for (int r = 0; r < 4; r++) {
        float mx = fmaxf(fmaxf(sv[qi][0][r], sv[qi][1][r]), fmaxf(sv[qi][2][r], sv[qi][3][r]));
#pragma unroll
        for (int msk = 1; msk < 16; msk <<= 1) mx = fmaxf(mx, __shfl_xor(mx, msk));
        const float mold = mrow[qi][r];
        const float mnew = fmaxf(mold, mx);
        const float corr = exp2f((mold - mnew) * LOG2E);
        mrow[qi][r] = mnew;
        lsum[qi][r] *= corr;
#pragma unroll
        for (int df = 0; df < 4; df++) o[qi][df][r] *= corr;
        float rsv = 0.f;
#pragma unroll
        for (int kf = 0; kf < 4; kf++) {
          const float p = exp2f((sv[qi][kf][r] - mnew) * LOG2E);
          sv[qi][kf][r] = p;
          rsv += p;
        }
#pragma unroll
        for (int msk = 1; msk < 16; msk <<= 1) rsv += __shfl_xor(rsv, msk);
        lsum[qi][r] += rsv;
      }
      // P -> per-wave LDS (bf16)
#pragma unroll
      for (int kf = 0; kf < 4; kf++)
#pragma unroll
        for (int r = 0; r < 4; r++)
          *((u16*)((char*)Plw + (qi * 16 + lg * 4 + r) * 144 + (kf * 16 + lrow) * 2)) =
              f2bf(sv[qi][kf][r]);
    }
    // O += P V
#pragma unroll
    for (int kc = 0; kc < 2; kc++) {
      bf16x8 pa[2], vb[4];
#pragma unroll
      for (int qi = 0; qi < 2; qi++)
        pa[qi] = *(const bf16x8*)((char*)Plw + (qi * 16 + lrow) * 144 + kc * 64 + lg * 16);
#pragma unroll
      for (int df = 0; df < 4; df++)
        vb[df] = *(const bf16x8*)((char*)Vt + (df * 16 + lrow) * 144 + kc * 64 + lg * 16);
#pragma unroll
      for (int qi = 0; qi < 2; qi++)
#pragma unroll
        for (int df = 0; df < 4; df++)
          o[qi][df] = __builtin_amdgcn_mfma_f32_16x16x32_bf16(pa[qi], vb[df], o[qi][df], 0, 0, 0);
    }
    __syncthreads();
  }
  // normalize + store
#pragma unroll
  for (int qi = 0; qi < 2; qi++)
#pragma unroll
    for (int df = 0; df < 4; df++) {
      const int col = h * 64 + df * 16 + lrow;
#pragma unroll
      for (int r = 0; r < 4; r++) {
        const int qg = qrow0 + qi * 16 + lg * 4 + r;
        const float val = o[qi][df][r] / lsum[qi][r];
        out[(size_t)(bat * S + qg) * 1024 + col] = f2bf(val);
      }
    }
}

// ---------------- host launch ----------------
extern "C" void kernel_launch(void* const* d_in, const int* in_sizes, int n_in,
                              void* d_out, int out_size, void* d_ws, size_t ws_size,
                              hipStream_t stream) {
  (void)in_sizes; (void)n_in; (void)out_size; (void)ws_size;
  const float* x      = (const float*)d_in[0];
  const float* ln1_g  = (const float*)d_in[1];
  const float* ln1_b  = (const float*)d_in[2];
  const float* W_attn = (const float*)d_in[3];
  const float* b_attn = (const float*)d_in[4];
  const float* W_proj = (const float*)d_in[5];
  const float* b_proj = (const float*)d_in[6];
  const float* ln2_g  = (const float*)d_in[7];
  const float* ln2_b  = (const float*)d_in[8];
  const float* W_fc   = (const float*)d_in[9];
  const float* b_fc   = (const float*)d_in[10];
  const float* W_mlp  = (const float*)d_in[11];
  const float* b_mlp  = (const float*)d_in[12];

  const int M = 4096;  // B*S = 2*2048
  char* ws = (char*)d_ws;
  size_t off = 0;
  auto alloc = [&](size_t bytes) {
    void* p = ws + off;
    off += (bytes + 255) & ~(size_t)255;
    return p;
  };
  u16* WattnT = (u16*)alloc((size_t)3072 * 1024 * 2);
  u16* WprojT = (u16*)alloc((size_t)1024 * 1024 * 2);
  u16* WfcT   = (u16*)alloc((size_t)4096 * 1024 * 2);
  u16* WmlpT  = (u16*)alloc((size_t)1024 * 4096 * 2);
  u16* x1     = (u16*)alloc((size_t)M * 1024 * 2);
  u16* qkvb   = (u16*)alloc((size_t)M * 3072 * 2);
  u16* attno  = (u16*)alloc((size_t)M * 1024 * 2);
  float* x2   = (float*)alloc((size_t)M * 1024 * 4);
  u16* x3     = (u16*)alloc((size_t)M * 1024 * 2);
  u16* hbuf   = (u16*)alloc((size_t)M * 4096 * 2);

  const dim3 blk(256);
  k_transpose_bf16<<<dim3(3072 / 32, 1024 / 32), blk, 0, stream>>>(W_attn, WattnT, 1024, 3072);
  k_transpose_bf16<<<dim3(1024 / 32, 1024 / 32), blk, 0, stream>>>(W_proj, WprojT, 1024, 1024);
  k_transpose_bf16<<<dim3(4096 / 32, 1024 / 32), blk, 0, stream>>>(W_fc, WfcT, 1024, 4096);
  k_transpose_bf16<<<dim3(1024 / 32, 4096 / 32), blk, 0, stream>>>(W_mlp, WmlpT, 4096, 1024);

  k_layernorm_bf16<<<M, blk, 0, stream>>>(x, ln1_g, ln1_b, x1);
  k_gemm_bt<0><<<dim3(3072 / 128, M / 128), blk, 0, stream>>>(x1, WattnT, b_attn, nullptr, qkvb, M, 3072, 1024);
  k_attention<<<dim3(16, 32), blk, 0, stream>>>(qkvb, attno);
  k_gemm_bt<1><<<dim3(1024 / 128, M / 128), blk, 0, stream>>>(attno, WprojT, b_proj, x1, x2, M, 1024, 1024);
  k_layernorm_bf16<<<M, blk, 0, stream>>>(x2, ln2_g, ln2_b, x3);
  k_gemm_bt<2><<<dim3(4096 / 128, M / 128), blk, 0, stream>>>(x3, WfcT, b_fc, nullptr, hbuf, M, 4096, 1024);
  k_gemm_bt<1><<<dim3(1024 / 128, M / 128), blk, 0, stream>>>(hbuf, WmlpT, b_mlp, x3, d_out, M, 1024, 4096);
}

// Round 2
// 310.196 us; speedup vs baseline: 1.3546x; 1.3546x over previous
//
#include <hip/hip_runtime.h>
#include <cstdint>

typedef __attribute__((ext_vector_type(8))) short bf16x8;
typedef __attribute__((ext_vector_type(4))) float f32x4;
typedef __attribute__((ext_vector_type(4))) unsigned short u16x4;
typedef unsigned short u16;

#define LOG2E 1.44269504088896340736f

__device__ __forceinline__ u16 f2bf(float f) {
  unsigned u = __builtin_bit_cast(unsigned, f);
  u += 0x7FFFu + ((u >> 16) & 1u);
  return (u16)(u >> 16);
}
__device__ __forceinline__ float bf2f(u16 h) {
  return __builtin_bit_cast(float, ((unsigned)h) << 16);
}

#define GLOAD_LDS16(g, l)                                                              \
  __builtin_amdgcn_global_load_lds((const __attribute__((address_space(1))) void*)(g), \
                                   (__attribute__((address_space(3))) void*)(l), 16, 0, 0)

// ---------------- weight transpose f32[K][N] -> bf16[N][K] ----------------
__global__ __launch_bounds__(256) void k_transpose_bf16(
    const float* __restrict__ W, u16* __restrict__ Wt, int K, int N) {
  __shared__ float tile[32][33];
  const int tid = threadIdx.x;
  const int tx = tid & 31, ty = tid >> 5;
  const int n0 = blockIdx.x * 32, k0 = blockIdx.y * 32;
#pragma unroll
  for (int i = 0; i < 32; i += 8)
    tile[ty + i][tx] = W[(size_t)(k0 + ty + i) * N + n0 + tx];
  __syncthreads();
#pragma unroll
  for (int i = 0; i < 32; i += 8)
    Wt[(size_t)(n0 + ty + i) * K + k0 + tx] = f2bf(tile[tx][ty + i]);
}

// ---------------- LayerNorm f32[row][1024] -> bf16 ----------------
__global__ __launch_bounds__(256) void k_layernorm_bf16(
    const float* __restrict__ x, const float* __restrict__ g,
    const float* __restrict__ b, u16* __restrict__ y) {
  const int row = blockIdx.x, tid = threadIdx.x;
  const float4 v = ((const float4*)(x + (size_t)row * 1024))[tid];
  float s = v.x + v.y + v.z + v.w;
#pragma unroll
  for (int m = 1; m < 64; m <<= 1) s += __shfl_xor(s, m);
  __shared__ float ps[8];
  if ((tid & 63) == 0) ps[tid >> 6] = s;
  __syncthreads();
  const float mean = (ps[0] + ps[1] + ps[2] + ps[3]) * (1.0f / 1024.0f);
  const float d0 = v.x - mean, d1 = v.y - mean, d2 = v.z - mean, d3 = v.w - mean;
  float s2 = d0 * d0 + d1 * d1 + d2 * d2 + d3 * d3;
#pragma unroll
  for (int m = 1; m < 64; m <<= 1) s2 += __shfl_xor(s2, m);
  if ((tid & 63) == 0) ps[4 + (tid >> 6)] = s2;
  __syncthreads();
  const float var = (ps[4] + ps[5] + ps[6] + ps[7]) * (1.0f / 1024.0f);
  const float rstd = rsqrtf(var + 1e-5f);
  const float4 gv = ((const float4*)g)[tid];
  const float4 bv = ((const float4*)b)[tid];
  u16x4 o;
  o[0] = f2bf(d0 * rstd * gv.x + bv.x);
  o[1] = f2bf(d1 * rstd * gv.y + bv.y);
  o[2] = f2bf(d2 * rstd * gv.z + bv.z);
  o[3] = f2bf(d3 * rstd * gv.w + bv.w);
  *(u16x4*)(y + (size_t)row * 1024 + tid * 4) = o;
}

__device__ __forceinline__ float gelu_f(float x) {
  const float u = 0.7978845608028654f * (x + 0.044715f * x * x * x);
  const float e = exp2f(u * 2.8853900817779268f);  // e^{2u}
  const float t = 1.0f - 2.0f / (e + 1.0f);        // tanh(u)
  return 0.5f * x * (1.0f + t);
}

// ---------------- GEMM: C[M,N] = A[M,K](bf16) * Bt[N,K]^T(bf16) + bias ----------------
// EPI 0: bf16 out
// EPI 1: f32 out + bf16 residual
// EPI 2: bf16 out + gelu
// EPI 3: qkv split: cols [0,2048) -> bf16 out with row-stride 2048 (Q|K);
//        cols [2048,3072) -> vt transposed per head: vt[(bat*16+h)*64+d][2048] = V[tok]
template <int EPI>
__global__ __launch_bounds__(256, 2) void k_gemm_bt(
    const u16* __restrict__ A, const u16* __restrict__ Bt,
    const float* __restrict__ bias, const u16* __restrict__ resid,
    void* __restrict__ out, u16* __restrict__ vt, int M, int N, int K) {
  __shared__ u16 As[128 * 64];
  __shared__ u16 Bs[128 * 64];
  const int tid = threadIdx.x;
  const int rowBase = blockIdx.y * 128, colBase = blockIdx.x * 128;
  const int w = tid >> 6, l = tid & 63;
  const int wm = w >> 1, wn = w & 1;
  const int lrow = l & 15, lg = l >> 4;
  const int srow = tid >> 3, sslot = tid & 7;

  const f32x4 fz = {0.f, 0.f, 0.f, 0.f};
  f32x4 acc[4][4];
#pragma unroll
  for (int m = 0; m < 4; m++)
#pragma unroll
    for (int n = 0; n < 4; n++) acc[m][n] = fz;

  for (int kt = 0; kt < K; kt += 64) {
#pragma unroll
    for (int i = 0; i < 4; i++) {
      const int r = srow + 32 * i;
      const int gs = sslot ^ (r & 7);  // inverse-swizzled source, linear LDS dest
      GLOAD_LDS16(A + (size_t)(rowBase + r) * K + kt + gs * 8, (char*)As + i * 4096 + tid * 16);
      GLOAD_LDS16(Bt + (size_t)(colBase + r) * K + kt + gs * 8, (char*)Bs + i * 4096 + tid * 16);
    }
    __syncthreads();
#pragma unroll
    for (int kc = 0; kc < 2; kc++) {
      bf16x8 av[4], bv[4];
#pragma unroll
      for (int m = 0; m < 4; m++) {
        const int r = wm * 64 + m * 16 + lrow;
        const int sl = (kc * 4 + lg) ^ (r & 7);
        av[m] = *(const bf16x8*)((const char*)As + r * 128 + sl * 16);
      }
#pragma unroll
      for (int n = 0; n < 4; n++) {
        const int r = wn * 64 + n * 16 + lrow;
        const int sl = (kc * 4 + lg) ^ (r & 7);
        bv[n] = *(const bf16x8*)((const char*)Bs + r * 128 + sl * 16);
      }
#pragma unroll
      for (int m = 0; m < 4; m++)
#pragma unroll
        for (int n = 0; n < 4; n++)
          acc[m][n] = __builtin_amdgcn_mfma_f32_16x16x32_bf16(av[m], bv[n], acc[m][n], 0, 0, 0);
    }
    __syncthreads();
  }
#pragma unroll
  for (int n = 0; n < 4; n++) {
    const int col = colBase + wn * 64 + n * 16 + lrow;
    const float bval = bias[col];
#pragma unroll
    for (int m = 0; m < 4; m++) {
      const int row0 = rowBase + wm * 64 + m * 16 + lg * 4;
      if (EPI == 3 && col >= 2048) {
        const int c2 = col - 2048;
        const int hh = c2 >> 6, dd = c2 & 63;
        const int bat = row0 >> 11, tok0 = row0 & 2047;
        u16x4 pk;
#pragma unroll
        for (int r = 0; r < 4; r++) pk[r] = f2bf(acc[m][n][r] + bval);
        *(u16x4*)(vt + ((size_t)(bat * 16 + hh) * 64 + dd) * 2048 + tok0) = pk;
      } else if (EPI == 3) {
#pragma unroll
        for (int r = 0; r < 4; r++)
          ((u16*)out)[(size_t)(row0 + r) * 2048 + col] = f2bf(acc[m][n][r] + bval);
      } else {
#pragma unroll
        for (int r = 0; r < 4; r++) {
          const size_t idx = (size_t)(row0 + r) * N + col;
          float v = acc[m][n][r] + bval;
          if (EPI == 0) {
            ((u16*)out)[idx] = f2bf(v);
          } else if (EPI == 2) {
            ((u16*)out)[idx] = f2bf(gelu_f(v));
          } else {
            v += bf2f(resid[idx]);
            ((float*)out)[idx] = v;
          }
        }
      }
    }
  }
}

// ---------------- causal flash attention v2 ----------------
// qk bf16 [B*S][2048] (q|k, each 1024 = 16 heads * 64)
// VT bf16 [B*H*64][2048]  (per-head transposed V: [d][tok])
// out bf16 [B*S][1024]
// grid: 1024 blocks; bid -> qt = 31-(bid>>5) (LPT), bh = bid&31 (XCD locality)
__global__ __launch_bounds__(256, 4) void k_attention(
    const u16* __restrict__ qk, const u16* __restrict__ VT, u16* __restrict__ out) {
  const int S = 2048, E2 = 2048;
  const int bid = blockIdx.x;
  const int qt = 31 - (bid >> 5);
  const int bh = bid & 31;
  const int bat = bh >> 4, h = bh & 15;
  const u16* base = qk + (size_t)bat * S * E2;
  const u16* kbase = base + 1024 + h * 64;
  const u16* vbase = VT + (size_t)bh * 64 * S;  // [d][tok]
  const int tid = threadIdx.x, w = tid >> 6, l = tid & 63;
  const int lrow = l & 15, lg = l >> 4;
  __shared__ u16 Ks[64 * 64];     // [key][d/8 slots] linear, content swizzled
  __shared__ u16 Vs[64 * 64];     // [d][key/8 slots]
  __shared__ u16 Pl[4][16 * 64];  // per-wave P [q][k], swizzled
  u16* Plw = Pl[w];
  const int qrow0 = qt * 64 + w * 16;

  // Q fragments held in registers for the whole block
  bf16x8 qfrag[2];
#pragma unroll
  for (int kc = 0; kc < 2; kc++)
    qfrag[kc] = *(const bf16x8*)(base + (size_t)(qrow0 + lrow) * E2 + h * 64 + kc * 32 + lg * 8);

  const f32x4 fz = {0.f, 0.f, 0.f, 0.f};
  f32x4 o[4];
  float mrow[4], lsum[4];
#pragma unroll
  for (int r = 0; r < 4; r++) { mrow[r] = -1e30f; lsum[r] = 0.f; }
#pragma unroll
  for (int df = 0; df < 4; df++) o[df] = fz;

  const int srow = tid >> 3, sslot = tid & 7;
  const int gs = sslot ^ (srow & 7);
  const int nkt = qt + 1;
  for (int kt = 0; kt < nkt; kt++) {
    const int kb = kt * 64;
    // stage K [key][d] and V^T [d][key] via global_load_lds, swizzled source
#pragma unroll
    for (int round = 0; round < 2; round++) {
      const int r = srow + 32 * round;
      GLOAD_LDS16(kbase + (size_t)(kb + r) * E2 + gs * 8, (char*)Ks + round * 4096 + tid * 16);
      GLOAD_LDS16(vbase + (size_t)r * S + kb + gs * 8, (char*)Vs + round * 4096 + tid * 16);
    }
    __syncthreads();
    // S = Q K^T   (D: row = q = lg*4+r, col = key = kf*16+lrow)
    f32x4 sv[4];
#pragma unroll
    for (int kf = 0; kf < 4; kf++) sv[kf] = fz;
#pragma unroll
    for (int kc = 0; kc < 2; kc++) {
      bf16x8 kfr[4];
#pragma unroll
      for (int kf = 0; kf < 4; kf++) {
        const int rk = kf * 16 + lrow;
        kfr[kf] = *(const bf16x8*)(Ks + rk * 64 + ((kc * 4 + lg) ^ (rk & 7)) * 8);
      }
#pragma unroll
      for (int kf = 0; kf < 4; kf++)
        sv[kf] = __builtin_amdgcn_mfma_f32_16x16x32_bf16(qfrag[kc], kfr[kf], sv[kf], 0, 0, 0);
    }
    // scale + causal mask
#pragma unroll
    for (int kf = 0; kf < 4; kf++) {
      const int kg = kb + kf * 16 + lrow;
#pragma unroll
      for (int r = 0; r < 4; r++) {
        const int qg = qrow0 + lg * 4 + r;
        const float xv = sv[kf][r] * 0.125f;
        sv[kf][r] = (kg > qg) ? -1e30f : xv;
      }
    }
    // online softmax (reduce over 16 col-lanes)
#pragma unroll
    for (int r = 0; r < 4; r++) {
      float mx = fmaxf(fmaxf(sv[0][r], sv[1][r]), fmaxf(sv[2][r], sv[3][r]));
#pragma unroll
      for (int msk = 1; msk < 16; msk <<= 1) mx = fmaxf(mx, __shfl_xor(mx, msk));
      const float mnew = fmaxf(mrow[r], mx);
      const float corr = exp2f((mrow[r] - mnew) * LOG2E);
      mrow[r] = mnew;
      lsum[r] *= corr;
#pragma unroll
      for (int df = 0; df < 4; df++) o[df][r] *= corr;
      float rsv = 0.f;
#pragma unroll
      for (int kf = 0; kf < 4; kf++) {
        const float p = exp2f((sv[kf][r] - mnew) * LOG2E);
        sv[kf][r] = p;
        rsv += p;
      }
#pragma unroll
      for (int msk = 1; msk < 16; msk <<= 1) rsv += __shfl_xor(rsv, msk);
      lsum[r] += rsv;
    }
    // P -> per-wave LDS (bf16, swizzled)
#pragma unroll
    for (int kf = 0; kf < 4; kf++)
#pragma unroll
      for (int r = 0; r < 4; r++) {
        const int q = lg * 4 + r;
        *(u16*)((char*)Plw + q * 128 + ((kf * 32 + lrow * 2) ^ ((q & 7) << 4))) = f2bf(sv[kf][r]);
      }
    // O += P V
#pragma unroll
    for (int kc = 0; kc < 2; kc++) {
      const bf16x8 pa =
          *(const bf16x8*)((const char*)Plw + lrow * 128 + (((kc * 4 + lg) ^ (lrow & 7)) << 4));
      bf16x8 vb[4];
#pragma unroll
      for (int df = 0; df < 4; df++) {
        const int rd = df * 16 + lrow;
        vb[df] = *(const bf16x8*)(Vs + rd * 64 + ((kc * 4 + lg) ^ (rd & 7)) * 8);
      }
#pragma unroll
      for (int df = 0; df < 4; df++)
        o[df] = __builtin_amdgcn_mfma_f32_16x16x32_bf16(pa, vb[df], o[df], 0, 0, 0);
    }
    __syncthreads();
  }
  // normalize + store
#pragma unroll
  for (int df = 0; df < 4; df++) {
    const int col = h * 64 + df * 16 + lrow;
#pragma unroll
    for (int r = 0; r < 4; r++) {
      const int qg = qrow0 + lg * 4 + r;
      out[(size_t)(bat * S + qg) * 1024 + col] = f2bf(o[df][r] / lsum[r]);
    }
  }
}

// ---------------- host launch ----------------
extern "C" void kernel_launch(void* const* d_in, const int* in_sizes, int n_in,
                              void* d_out, int out_size, void* d_ws, size_t ws_size,
                              hipStream_t stream) {
  (void)in_sizes; (void)n_in; (void)out_size; (void)ws_size;
  const float* x      = (const float*)d_in[0];
  const float* ln1_g  = (const float*)d_in[1];
  const float* ln1_b  = (const float*)d_in[2];
  const float* W_attn = (const float*)d_in[3];
  const float* b_attn = (const float*)d_in[4];
  const float* W_proj = (const float*)d_in[5];
  const float* b_proj = (const float*)d_in[6];
  const float* ln2_g  = (const float*)d_in[7];
  const float* ln2_b  = (const float*)d_in[8];
  const float* W_fc   = (const float*)d_in[9];
  const float* b_fc   = (const float*)d_in[10];
  const float* W_mlp  = (const float*)d_in[11];
  const float* b_mlp  = (const float*)d_in[12];

  const int M = 4096;  // B*S = 2*2048
  char* ws = (char*)d_ws;
  size_t off = 0;
  auto alloc = [&](size_t bytes) {
    void* p = ws + off;
    off += (bytes + 255) & ~(size_t)255;
    return p;
  };
  u16* WattnT = (u16*)alloc((size_t)3072 * 1024 * 2);
  u16* WprojT = (u16*)alloc((size_t)1024 * 1024 * 2);
  u16* WfcT   = (u16*)alloc((size_t)4096 * 1024 * 2);
  u16* WmlpT  = (u16*)alloc((size_t)1024 * 4096 * 2);
  u16* x1     = (u16*)alloc((size_t)M * 1024 * 2);
  u16* qkb    = (u16*)alloc((size_t)M * 2048 * 2);   // Q|K only
  u16* VT     = (u16*)alloc((size_t)32 * 64 * 2048 * 2);  // [b*h][d][tok]
  u16* attno  = (u16*)alloc((size_t)M * 1024 * 2);
  float* x2   = (float*)alloc((size_t)M * 1024 * 4);
  u16* x3     = (u16*)alloc((size_t)M * 1024 * 2);
  u16* hbuf   = (u16*)alloc((size_t)M * 4096 * 2);

  const dim3 blk(256);
  k_transpose_bf16<<<dim3(3072 / 32, 1024 / 32), blk, 0, stream>>>(W_attn, WattnT, 1024, 3072);
  k_transpose_bf16<<<dim3(1024 / 32, 1024 / 32), blk, 0, stream>>>(W_proj, WprojT, 1024, 1024);
  k_transpose_bf16<<<dim3(4096 / 32, 1024 / 32), blk, 0, stream>>>(W_fc, WfcT, 1024, 4096);
  k_transpose_bf16<<<dim3(1024 / 32, 4096 / 32), blk, 0, stream>>>(W_mlp, WmlpT, 4096, 1024);

  k_layernorm_bf16<<<M, blk, 0, stream>>>(x, ln1_g, ln1_b, x1);
  k_gemm_bt<3><<<dim3(3072 / 128, M / 128), blk, 0, stream>>>(x1, WattnT, b_attn, nullptr, qkb, VT, M, 3072, 1024);
  k_attention<<<dim3(1024), blk, 0, stream>>>(qkb, VT, attno);
  k_gemm_bt<1><<<dim3(1024 / 128, M / 128), blk, 0, stream>>>(attno, WprojT, b_proj, x1, x2, nullptr, M, 1024, 1024);
  k_layernorm_bf16<<<M, blk, 0, stream>>>(x2, ln2_g, ln2_b, x3);
  k_gemm_bt<2><<<dim3(4096 / 128, M / 128), blk, 0, stream>>>(x3, WfcT, b_fc, nullptr, hbuf, nullptr, M, 4096, 1024);
  k_gemm_bt<1><<<dim3(1024 / 128, M / 128), blk, 0, stream>>>(hbuf, WmlpT, b_mlp, x3, d_out, nullptr, M, 1024, 4096);
}

// Round 3
// 300.724 us; speedup vs baseline: 1.3972x; 1.0315x over previous
//
#include <hip/hip_runtime.h>
#include <cstdint>

typedef __attribute__((ext_vector_type(8))) short bf16x8;
typedef __attribute__((ext_vector_type(4))) float f32x4;
typedef __attribute__((ext_vector_type(4))) unsigned short u16x4;
typedef unsigned short u16;

#define LOG2E 1.44269504088896340736f

__device__ __forceinline__ u16 f2bf(float f) {
  unsigned u = __builtin_bit_cast(unsigned, f);
  u += 0x7FFFu + ((u >> 16) & 1u);
  return (u16)(u >> 16);
}
__device__ __forceinline__ float bf2f(u16 h) {
  return __builtin_bit_cast(float, ((unsigned)h) << 16);
}

#define GLOAD_LDS16(g, l)                                                              \
  __builtin_amdgcn_global_load_lds((const __attribute__((address_space(1))) void*)(g), \
                                   (__attribute__((address_space(3))) void*)(l), 16, 0, 0)

// ---------------- weight transpose f32[K][N] -> bf16[N][K] ----------------
__global__ __launch_bounds__(256) void k_transpose_bf16(
    const float* __restrict__ W, u16* __restrict__ Wt, int K, int N) {
  __shared__ float tile[32][33];
  const int tid = threadIdx.x;
  const int tx = tid & 31, ty = tid >> 5;
  const int n0 = blockIdx.x * 32, k0 = blockIdx.y * 32;
#pragma unroll
  for (int i = 0; i < 32; i += 8)
    tile[ty + i][tx] = W[(size_t)(k0 + ty + i) * N + n0 + tx];
  __syncthreads();
#pragma unroll
  for (int i = 0; i < 32; i += 8)
    Wt[(size_t)(n0 + ty + i) * K + k0 + tx] = f2bf(tile[tx][ty + i]);
}

// ---------------- LayerNorm f32[row][1024] -> bf16 ----------------
__global__ __launch_bounds__(256) void k_layernorm_bf16(
    const float* __restrict__ x, const float* __restrict__ g,
    const float* __restrict__ b, u16* __restrict__ y) {
  const int row = blockIdx.x, tid = threadIdx.x;
  const float4 v = ((const float4*)(x + (size_t)row * 1024))[tid];
  float s = v.x + v.y + v.z + v.w;
#pragma unroll
  for (int m = 1; m < 64; m <<= 1) s += __shfl_xor(s, m);
  __shared__ float ps[8];
  if ((tid & 63) == 0) ps[tid >> 6] = s;
  __syncthreads();
  const float mean = (ps[0] + ps[1] + ps[2] + ps[3]) * (1.0f / 1024.0f);
  const float d0 = v.x - mean, d1 = v.y - mean, d2 = v.z - mean, d3 = v.w - mean;
  float s2 = d0 * d0 + d1 * d1 + d2 * d2 + d3 * d3;
#pragma unroll
  for (int m = 1; m < 64; m <<= 1) s2 += __shfl_xor(s2, m);
  if ((tid & 63) == 0) ps[4 + (tid >> 6)] = s2;
  __syncthreads();
  const float var = (ps[4] + ps[5] + ps[6] + ps[7]) * (1.0f / 1024.0f);
  const float rstd = rsqrtf(var + 1e-5f);
  const float4 gv = ((const float4*)g)[tid];
  const float4 bv = ((const float4*)b)[tid];
  u16x4 o;
  o[0] = f2bf(d0 * rstd * gv.x + bv.x);
  o[1] = f2bf(d1 * rstd * gv.y + bv.y);
  o[2] = f2bf(d2 * rstd * gv.z + bv.z);
  o[3] = f2bf(d3 * rstd * gv.w + bv.w);
  *(u16x4*)(y + (size_t)row * 1024 + tid * 4) = o;
}

__device__ __forceinline__ float gelu_f(float x) {
  const float u = 0.7978845608028654f * (x + 0.044715f * x * x * x);
  const float e = exp2f(u * 2.8853900817779268f);  // e^{2u}
  const float t = 1.0f - 2.0f / (e + 1.0f);        // tanh(u)
  return 0.5f * x * (1.0f + t);
}

// ---------------- GEMM: C[M,N] = A[M,K](bf16) * Bt[N,K]^T(bf16) + bias ----------------
// EPI 0: bf16 out
// EPI 1: f32 out + bf16 residual
// EPI 2: bf16 out + gelu
// EPI 3: qkv split: cols [0,2048) -> bf16 out with row-stride 2048 (Q|K);
//        cols [2048,3072) -> vt transposed per head: vt[(bat*16+h)*64+d][2048] = V[tok]
template <int EPI>
__global__ __launch_bounds__(256, 2) void k_gemm_bt(
    const u16* __restrict__ A, const u16* __restrict__ Bt,
    const float* __restrict__ bias, const u16* __restrict__ resid,
    void* __restrict__ out, u16* __restrict__ vt, int M, int N, int K) {
  __shared__ u16 As[128 * 64];
  __shared__ u16 Bs[128 * 64];
  const int tid = threadIdx.x;
  const int rowBase = blockIdx.y * 128, colBase = blockIdx.x * 128;
  const int w = tid >> 6, l = tid & 63;
  const int wm = w >> 1, wn = w & 1;
  const int lrow = l & 15, lg = l >> 4;
  const int srow = tid >> 3, sslot = tid & 7;

  const f32x4 fz = {0.f, 0.f, 0.f, 0.f};
  f32x4 acc[4][4];
#pragma unroll
  for (int m = 0; m < 4; m++)
#pragma unroll
    for (int n = 0; n < 4; n++) acc[m][n] = fz;

  for (int kt = 0; kt < K; kt += 64) {
#pragma unroll
    for (int i = 0; i < 4; i++) {
      const int r = srow + 32 * i;
      const int gs = sslot ^ (r & 7);  // inverse-swizzled source, linear LDS dest
      GLOAD_LDS16(A + (size_t)(rowBase + r) * K + kt + gs * 8, (char*)As + i * 4096 + tid * 16);
      GLOAD_LDS16(Bt + (size_t)(colBase + r) * K + kt + gs * 8, (char*)Bs + i * 4096 + tid * 16);
    }
    __syncthreads();
#pragma unroll
    for (int kc = 0; kc < 2; kc++) {
      bf16x8 av[4], bv[4];
#pragma unroll
      for (int m = 0; m < 4; m++) {
        const int r = wm * 64 + m * 16 + lrow;
        const int sl = (kc * 4 + lg) ^ (r & 7);
        av[m] = *(const bf16x8*)((const char*)As + r * 128 + sl * 16);
      }
#pragma unroll
      for (int n = 0; n < 4; n++) {
        const int r = wn * 64 + n * 16 + lrow;
        const int sl = (kc * 4 + lg) ^ (r & 7);
        bv[n] = *(const bf16x8*)((const char*)Bs + r * 128 + sl * 16);
      }
#pragma unroll
      for (int m = 0; m < 4; m++)
#pragma unroll
        for (int n = 0; n < 4; n++)
          acc[m][n] = __builtin_amdgcn_mfma_f32_16x16x32_bf16(av[m], bv[n], acc[m][n], 0, 0, 0);
    }
    __syncthreads();
  }
#pragma unroll
  for (int n = 0; n < 4; n++) {
    const int col = colBase + wn * 64 + n * 16 + lrow;
    const float bval = bias[col];
#pragma unroll
    for (int m = 0; m < 4; m++) {
      const int row0 = rowBase + wm * 64 + m * 16 + lg * 4;
      if (EPI == 3 && col >= 2048) {
        const int c2 = col - 2048;
        const int hh = c2 >> 6, dd = c2 & 63;
        const int bat = row0 >> 11, tok0 = row0 & 2047;
        u16x4 pk;
#pragma unroll
        for (int r = 0; r < 4; r++) pk[r] = f2bf(acc[m][n][r] + bval);
        *(u16x4*)(vt + ((size_t)(bat * 16 + hh) * 64 + dd) * 2048 + tok0) = pk;
      } else if (EPI == 3) {
#pragma unroll
        for (int r = 0; r < 4; r++)
          ((u16*)out)[(size_t)(row0 + r) * 2048 + col] = f2bf(acc[m][n][r] + bval);
      } else {
#pragma unroll
        for (int r = 0; r < 4; r++) {
          const size_t idx = (size_t)(row0 + r) * N + col;
          float v = acc[m][n][r] + bval;
          if (EPI == 0) {
            ((u16*)out)[idx] = f2bf(v);
          } else if (EPI == 2) {
            ((u16*)out)[idx] = f2bf(gelu_f(v));
          } else {
            v += bf2f(resid[idx]);
            ((float*)out)[idx] = v;
          }
        }
      }
    }
  }
}

// ---------------- causal flash attention v3 ----------------
// qk bf16 [B*S][2048] (q|k, each 1024 = 16 heads * 64)
// VT bf16 [B*H*64][2048]  (per-head transposed V: [d][tok])
// out bf16 [B*S][1024]
// grid: 512 blocks; pid = bid>>5 in [0,16) -> q-tile pair (pid, 31-pid): uniform 33 tiles
// bh = bid&31 -> XCD = bid%8 = bh%8: per-XCD K/V L2 residency (4 heads x 512KB = 2MB)
__global__ __launch_bounds__(256, 2) void k_attention(
    const u16* __restrict__ qk, const u16* __restrict__ VT, u16* __restrict__ out) {
  const int S = 2048, E2 = 2048;
  const int bid = blockIdx.x;
  const int pid = bid >> 5;
  const int bh = bid & 31;
  const int bat = bh >> 4, h = bh & 15;
  const u16* base = qk + (size_t)bat * S * E2;
  const u16* kbase = base + 1024 + h * 64;
  const u16* vbase = VT + (size_t)bh * 64 * S;  // [d][tok]
  const int tid = threadIdx.x, w = tid >> 6, l = tid & 63;
  const int lrow = l & 15, lg = l >> 4;
  __shared__ u16 Ks[2][64 * 64];  // double-buffered [key][slot]
  __shared__ u16 Vs[2][64 * 64];  // double-buffered [d][slot]
  __shared__ u16 Pl[4][16 * 64];  // per-wave P [q][k], swizzled
  u16* Plw = Pl[w];
  const int srow = tid >> 3, sslot = tid & 7;
  const int gs = sslot ^ (srow & 7);
  const float sc = 0.125f * LOG2E;  // score -> log2 domain in one mul
  const f32x4 fz = {0.f, 0.f, 0.f, 0.f};

  auto STAGE = [&](int bufi, int kb) {
#pragma unroll
    for (int round = 0; round < 2; round++) {
      const int r = srow + 32 * round;
      GLOAD_LDS16(kbase + (size_t)(kb + r) * E2 + gs * 8, (char*)Ks[bufi] + round * 4096 + tid * 16);
      GLOAD_LDS16(vbase + (size_t)r * S + kb + gs * 8, (char*)Vs[bufi] + round * 4096 + tid * 16);
    }
  };

  for (int pass = 0; pass < 2; ++pass) {
    const int qt = pass ? (31 - pid) : pid;
    const int qrow0 = qt * 64 + w * 16;
    const int nkt = qt + 1;

    bf16x8 qfrag[2];
#pragma unroll
    for (int kc = 0; kc < 2; kc++)
      qfrag[kc] = *(const bf16x8*)(base + (size_t)(qrow0 + lrow) * E2 + h * 64 + kc * 32 + lg * 8);

    f32x4 o[4];
    float mrow[4], lsum[4];
#pragma unroll
    for (int r = 0; r < 4; r++) { mrow[r] = -1e30f; lsum[r] = 0.f; }
#pragma unroll
    for (int df = 0; df < 4; df++) o[df] = fz;

    STAGE(0, 0);
    __syncthreads();  // drains prologue loads (implicit vmcnt(0)) for all waves

    for (int kt = 0; kt < nkt; kt++) {
      const int cur = kt & 1;
      const int kb = kt * 64;
      if (kt + 1 < nkt) STAGE(cur ^ 1, kb + 64);  // prefetch next tile; hidden under compute
      const u16* Kc = Ks[cur];
      const u16* Vc = Vs[cur];

      // S = Q K^T   (D: row = q = lg*4+r, col = key = kf*16+lrow)
      f32x4 sv[4];
#pragma unroll
      for (int kf = 0; kf < 4; kf++) sv[kf] = fz;
#pragma unroll
      for (int kc = 0; kc < 2; kc++) {
        bf16x8 kfr[4];
#pragma unroll
        for (int kf = 0; kf < 4; kf++) {
          const int rk = kf * 16 + lrow;
          kfr[kf] = *(const bf16x8*)(Kc + rk * 64 + ((kc * 4 + lg) ^ (rk & 7)) * 8);
        }
#pragma unroll
        for (int kf = 0; kf < 4; kf++)
          sv[kf] = __builtin_amdgcn_mfma_f32_16x16x32_bf16(qfrag[kc], kfr[kf], sv[kf], 0, 0, 0);
      }
      // to log2 domain (single mul per element)
#pragma unroll
      for (int kf = 0; kf < 4; kf++)
#pragma unroll
        for (int r = 0; r < 4; r++) sv[kf][r] *= sc;
      // causal mask: only the diagonal tile needs it (wave-uniform branch)
      if (kt == nkt - 1) {
#pragma unroll
        for (int kf = 0; kf < 4; kf++) {
          const int kg = kb + kf * 16 + lrow;
#pragma unroll
          for (int r = 0; r < 4; r++) {
            const int qg = qrow0 + lg * 4 + r;
            if (kg > qg) sv[kf][r] = -1e30f;
          }
        }
      }
      // online softmax in log2 domain (reduce over 16 col-lanes)
#pragma unroll
      for (int r = 0; r < 4; r++) {
        float mx = fmaxf(fmaxf(sv[0][r], sv[1][r]), fmaxf(sv[2][r], sv[3][r]));
#pragma unroll
        for (int msk = 1; msk < 16; msk <<= 1) mx = fmaxf(mx, __shfl_xor(mx, msk));
        const float mnew = fmaxf(mrow[r], mx);
        const float corr = exp2f(mrow[r] - mnew);
        mrow[r] = mnew;
        lsum[r] *= corr;
#pragma unroll
        for (int df = 0; df < 4; df++) o[df][r] *= corr;
        float rsv = 0.f;
#pragma unroll
        for (int kf = 0; kf < 4; kf++) {
          const float p = exp2f(sv[kf][r] - mnew);
          sv[kf][r] = p;
          rsv += p;
        }
#pragma unroll
        for (int msk = 1; msk < 16; msk <<= 1) rsv += __shfl_xor(rsv, msk);
        lsum[r] += rsv;
      }
      // P -> per-wave LDS (bf16, swizzled)
#pragma unroll
      for (int kf = 0; kf < 4; kf++)
#pragma unroll
        for (int r = 0; r < 4; r++) {
          const int q = lg * 4 + r;
          *(u16*)((char*)Plw + q * 128 + ((kf * 32 + lrow * 2) ^ ((q & 7) << 4))) = f2bf(sv[kf][r]);
        }
      // O += P V
#pragma unroll
      for (int kc = 0; kc < 2; kc++) {
        const bf16x8 pa =
            *(const bf16x8*)((const char*)Plw + lrow * 128 + (((kc * 4 + lg) ^ (lrow & 7)) << 4));
        bf16x8 vb[4];
#pragma unroll
        for (int df = 0; df < 4; df++) {
          const int rd = df * 16 + lrow;
          vb[df] = *(const bf16x8*)(Vc + rd * 64 + ((kc * 4 + lg) ^ (rd & 7)) * 8);
        }
#pragma unroll
        for (int df = 0; df < 4; df++)
          o[df] = __builtin_amdgcn_mfma_f32_16x16x32_bf16(pa, vb[df], o[df], 0, 0, 0);
      }
      __syncthreads();  // one barrier/tile: vmcnt(0) drain of prefetch + buffer-reuse fence
    }
    // normalize + store
#pragma unroll
    for (int r = 0; r < 4; r++) {
      const float inv = 1.0f / lsum[r];
      const int qg = qrow0 + lg * 4 + r;
#pragma unroll
      for (int df = 0; df < 4; df++) {
        const int col = h * 64 + df * 16 + lrow;
        out[(size_t)(bat * S + qg) * 1024 + col] = f2bf(o[df][r] * inv);
      }
    }
  }
}

// ---------------- host launch ----------------
extern "C" void kernel_launch(void* const* d_in, const int* in_sizes, int n_in,
                              void* d_out, int out_size, void* d_ws, size_t ws_size,
                              hipStream_t stream) {
  (void)in_sizes; (void)n_in; (void)out_size; (void)ws_size;
  const float* x      = (const float*)d_in[0];
  const float* ln1_g  = (const float*)d_in[1];
  const float* ln1_b  = (const float*)d_in[2];
  const float* W_attn = (const float*)d_in[3];
  const float* b_attn = (const float*)d_in[4];
  const float* W_proj = (const float*)d_in[5];
  const float* b_proj = (const float*)d_in[6];
  const float* ln2_g  = (const float*)d_in[7];
  const float* ln2_b  = (const float*)d_in[8];
  const float* W_fc   = (const float*)d_in[9];
  const float* b_fc   = (const float*)d_in[10];
  const float* W_mlp  = (const float*)d_in[11];
  const float* b_mlp  = (const float*)d_in[12];

  const int M = 4096;  // B*S = 2*2048
  char* ws = (char*)d_ws;
  size_t off = 0;
  auto alloc = [&](size_t bytes) {
    void* p = ws + off;
    off += (bytes + 255) & ~(size_t)255;
    return p;
  };
  u16* WattnT = (u16*)alloc((size_t)3072 * 1024 * 2);
  u16* WprojT = (u16*)alloc((size_t)1024 * 1024 * 2);
  u16* WfcT   = (u16*)alloc((size_t)4096 * 1024 * 2);
  u16* WmlpT  = (u16*)alloc((size_t)1024 * 4096 * 2);
  u16* x1     = (u16*)alloc((size_t)M * 1024 * 2);
  u16* qkb    = (u16*)alloc((size_t)M * 2048 * 2);   // Q|K only
  u16* VT     = (u16*)alloc((size_t)32 * 64 * 2048 * 2);  // [b*h][d][tok]
  u16* attno  = (u16*)alloc((size_t)M * 1024 * 2);
  float* x2   = (float*)alloc((size_t)M * 1024 * 4);
  u16* x3     = (u16*)alloc((size_t)M * 1024 * 2);
  u16* hbuf   = (u16*)alloc((size_t)M * 4096 * 2);

  const dim3 blk(256);
  k_transpose_bf16<<<dim3(3072 / 32, 1024 / 32), blk, 0, stream>>>(W_attn, WattnT, 1024, 3072);
  k_transpose_bf16<<<dim3(1024 / 32, 1024 / 32), blk, 0, stream>>>(W_proj, WprojT, 1024, 1024);
  k_transpose_bf16<<<dim3(4096 / 32, 1024 / 32), blk, 0, stream>>>(W_fc, WfcT, 1024, 4096);
  k_transpose_bf16<<<dim3(1024 / 32, 4096 / 32), blk, 0, stream>>>(W_mlp, WmlpT, 4096, 1024);

  k_layernorm_bf16<<<M, blk, 0, stream>>>(x, ln1_g, ln1_b, x1);
  k_gemm_bt<3><<<dim3(3072 / 128, M / 128), blk, 0, stream>>>(x1, WattnT, b_attn, nullptr, qkb, VT, M, 3072, 1024);
  k_attention<<<dim3(512), blk, 0, stream>>>(qkb, VT, attno);
  k_gemm_bt<1><<<dim3(1024 / 128, M / 128), blk, 0, stream>>>(attno, WprojT, b_proj, x1, x2, nullptr, M, 1024, 1024);
  k_layernorm_bf16<<<M, blk, 0, stream>>>(x2, ln2_g, ln2_b, x3);
  k_gemm_bt<2><<<dim3(4096 / 128, M / 128), blk, 0, stream>>>(x3, WfcT, b_fc, nullptr, hbuf, nullptr, M, 4096, 1024);
  k_gemm_bt<1><<<dim3(1024 / 128, M / 128), blk, 0, stream>>>(hbuf, WmlpT, b_mlp, x3, d_out, nullptr, M, 1024, 4096);
}

// Round 4
// 290.193 us; speedup vs baseline: 1.4479x; 1.0363x over previous
//
#include <hip/hip_runtime.h>
#include <cstdint>

typedef __attribute__((ext_vector_type(8))) short bf16x8;
typedef __attribute__((ext_vector_type(4))) float f32x4;
typedef __attribute__((ext_vector_type(4))) unsigned short u16x4;
typedef unsigned short u16;

#define LOG2E 1.44269504088896340736f

__device__ __forceinline__ u16 f2bf(float f) {
  unsigned u = __builtin_bit_cast(unsigned, f);
  u += 0x7FFFu + ((u >> 16) & 1u);
  return (u16)(u >> 16);
}
__device__ __forceinline__ float bf2f(u16 h) {
  return __builtin_bit_cast(float, ((unsigned)h) << 16);
}

#define GLOAD_LDS16(g, l)                                                              \
  __builtin_amdgcn_global_load_lds((const __attribute__((address_space(1))) void*)(g), \
                                   (__attribute__((address_space(3))) void*)(l), 16, 0, 0)

// ---------------- weight transpose f32[K][N] -> bf16[N][K] ----------------
__global__ __launch_bounds__(256) void k_transpose_bf16(
    const float* __restrict__ W, u16* __restrict__ Wt, int K, int N) {
  __shared__ float tile[32][33];
  const int tid = threadIdx.x;
  const int tx = tid & 31, ty = tid >> 5;
  const int n0 = blockIdx.x * 32, k0 = blockIdx.y * 32;
#pragma unroll
  for (int i = 0; i < 32; i += 8)
    tile[ty + i][tx] = W[(size_t)(k0 + ty + i) * N + n0 + tx];
  __syncthreads();
#pragma unroll
  for (int i = 0; i < 32; i += 8)
    Wt[(size_t)(n0 + ty + i) * K + k0 + tx] = f2bf(tile[tx][ty + i]);
}

// ---------------- LayerNorm f32[row][1024] -> bf16 ----------------
__global__ __launch_bounds__(256) void k_layernorm_bf16(
    const float* __restrict__ x, const float* __restrict__ g,
    const float* __restrict__ b, u16* __restrict__ y) {
  const int row = blockIdx.x, tid = threadIdx.x;
  const float4 v = ((const float4*)(x + (size_t)row * 1024))[tid];
  float s = v.x + v.y + v.z + v.w;
#pragma unroll
  for (int m = 1; m < 64; m <<= 1) s += __shfl_xor(s, m);
  __shared__ float ps[8];
  if ((tid & 63) == 0) ps[tid >> 6] = s;
  __syncthreads();
  const float mean = (ps[0] + ps[1] + ps[2] + ps[3]) * (1.0f / 1024.0f);
  const float d0 = v.x - mean, d1 = v.y - mean, d2 = v.z - mean, d3 = v.w - mean;
  float s2 = d0 * d0 + d1 * d1 + d2 * d2 + d3 * d3;
#pragma unroll
  for (int m = 1; m < 64; m <<= 1) s2 += __shfl_xor(s2, m);
  if ((tid & 63) == 0) ps[4 + (tid >> 6)] = s2;
  __syncthreads();
  const float var = (ps[4] + ps[5] + ps[6] + ps[7]) * (1.0f / 1024.0f);
  const float rstd = rsqrtf(var + 1e-5f);
  const float4 gv = ((const float4*)g)[tid];
  const float4 bv = ((const float4*)b)[tid];
  u16x4 o;
  o[0] = f2bf(d0 * rstd * gv.x + bv.x);
  o[1] = f2bf(d1 * rstd * gv.y + bv.y);
  o[2] = f2bf(d2 * rstd * gv.z + bv.z);
  o[3] = f2bf(d3 * rstd * gv.w + bv.w);
  *(u16x4*)(y + (size_t)row * 1024 + tid * 4) = o;
}

__device__ __forceinline__ float gelu_f(float x) {
  const float u = 0.7978845608028654f * (x + 0.044715f * x * x * x);
  const float e = exp2f(u * 2.8853900817779268f);  // e^{2u}
  const float t = 1.0f - 2.0f / (e + 1.0f);        // tanh(u)
  return 0.5f * x * (1.0f + t);
}

// ---------------- 128x128 GEMM (2-phase, kept for small-N shapes) ----------------
// EPI 1: f32 out + bf16 residual
template <int EPI>
__global__ __launch_bounds__(256, 2) void k_gemm_bt(
    const u16* __restrict__ A, const u16* __restrict__ Bt,
    const float* __restrict__ bias, const u16* __restrict__ resid,
    void* __restrict__ out, u16* __restrict__ vt, int M, int N, int K) {
  __shared__ u16 As[128 * 64];
  __shared__ u16 Bs[128 * 64];
  const int tid = threadIdx.x;
  const int rowBase = blockIdx.y * 128, colBase = blockIdx.x * 128;
  const int w = tid >> 6, l = tid & 63;
  const int wm = w >> 1, wn = w & 1;
  const int lrow = l & 15, lg = l >> 4;
  const int srow = tid >> 3, sslot = tid & 7;

  const f32x4 fz = {0.f, 0.f, 0.f, 0.f};
  f32x4 acc[4][4];
#pragma unroll
  for (int m = 0; m < 4; m++)
#pragma unroll
    for (int n = 0; n < 4; n++) acc[m][n] = fz;

  for (int kt = 0; kt < K; kt += 64) {
#pragma unroll
    for (int i = 0; i < 4; i++) {
      const int r = srow + 32 * i;
      const int gs = sslot ^ (r & 7);  // inverse-swizzled source, linear LDS dest
      GLOAD_LDS16(A + (size_t)(rowBase + r) * K + kt + gs * 8, (char*)As + i * 4096 + tid * 16);
      GLOAD_LDS16(Bt + (size_t)(colBase + r) * K + kt + gs * 8, (char*)Bs + i * 4096 + tid * 16);
    }
    __syncthreads();
#pragma unroll
    for (int kc = 0; kc < 2; kc++) {
      bf16x8 av[4], bv[4];
#pragma unroll
      for (int m = 0; m < 4; m++) {
        const int r = wm * 64 + m * 16 + lrow;
        const int sl = (kc * 4 + lg) ^ (r & 7);
        av[m] = *(const bf16x8*)((const char*)As + r * 128 + sl * 16);
      }
#pragma unroll
      for (int n = 0; n < 4; n++) {
        const int r = wn * 64 + n * 16 + lrow;
        const int sl = (kc * 4 + lg) ^ (r & 7);
        bv[n] = *(const bf16x8*)((const char*)Bs + r * 128 + sl * 16);
      }
#pragma unroll
      for (int m = 0; m < 4; m++)
#pragma unroll
        for (int n = 0; n < 4; n++)
          acc[m][n] = __builtin_amdgcn_mfma_f32_16x16x32_bf16(av[m], bv[n], acc[m][n], 0, 0, 0);
    }
    __syncthreads();
  }
#pragma unroll
  for (int n = 0; n < 4; n++) {
    const int col = colBase + wn * 64 + n * 16 + lrow;
    const float bval = bias[col];
#pragma unroll
    for (int m = 0; m < 4; m++) {
      const int row0 = rowBase + wm * 64 + m * 16 + lg * 4;
#pragma unroll
      for (int r = 0; r < 4; r++) {
        const size_t idx = (size_t)(row0 + r) * N + col;
        float v = acc[m][n][r] + bval;
        if (EPI == 0) {
          ((u16*)out)[idx] = f2bf(v);
        } else if (EPI == 2) {
          ((u16*)out)[idx] = f2bf(gelu_f(v));
        } else {
          v += bf2f(resid[idx]);
          ((float*)out)[idx] = v;
        }
      }
    }
  }
}

// ---------------- 256x256 8-phase GEMM (T2+T3+T4+T5), 512 thr, 128KB LDS ----------
// EPI 2: bf16 out + gelu
// EPI 3: qkv split epilogue (Q|K row-stride 2048; V transposed per head into vt)
// LDS map: A: [buf2][half2][128 rows][8 slots*16B]  (64KB)   swz: slot^(row&7)
//          B: [buf2][ksl2][256 rows][4 slots*16B]   (64KB)   swz: slot^((row>>1)&3)
// Per K-tile: 4 phases; counted waits vmcnt(2) pre-ph0, vmcnt(4) pre-ph2 (never 0
// in steady state). Stage order A-lo,A-hi,B-k0,B-k1 matches consumption order.
template <int EPI>
__global__ __launch_bounds__(512, 2) void k_gemm8(
    const u16* __restrict__ A, const u16* __restrict__ Bt,
    const float* __restrict__ bias, void* __restrict__ out,
    u16* __restrict__ vt, int M, int N, int K, int nbx) {
  extern __shared__ char sm[];
  char* smA = sm;
  char* smB = sm + 65536;
  const int tid = threadIdx.x;
  // bijective XCD swizzle (gridDim.x % 8 == 0 guaranteed by caller)
  const int q8 = gridDim.x >> 3;
  const int wg = (blockIdx.x & 7) * q8 + (blockIdx.x >> 3);
  const int bx = wg % nbx, by = wg / nbx;
  const int rowBase = by * 256, colBase = bx * 256;
  const int w = tid >> 6, l = tid & 63;
  const int wm = w >> 2, wn = w & 3;
  const int lrow = l & 15, lg = l >> 4;

  // staging address constants
  const int sArow = tid >> 3;
  const int gsA = (tid & 7) ^ (sArow & 7);
  const int sBrow = tid >> 2;
  const int gsB = (tid & 3) ^ ((tid >> 3) & 3);
  const u16* Ag = A + (size_t)(rowBase + sArow) * K + gsA * 8;
  const u16* Bg = Bt + (size_t)(colBase + sBrow) * K + gsB * 8;

#define STAGE_A8(buf, half, kt)                                                         \
  do {                                                                                  \
    GLOAD_LDS16(Ag + ((size_t)(half)*128) * K + (kt)*64,                                \
                smA + (buf)*32768 + (half)*16384 + tid * 16);                           \
    GLOAD_LDS16(Ag + ((size_t)(half)*128 + 64) * K + (kt)*64,                           \
                smA + (buf)*32768 + (half)*16384 + 8192 + tid * 16);                    \
  } while (0)
#define STAGE_B8(buf, ksl, kt)                                                          \
  do {                                                                                  \
    GLOAD_LDS16(Bg + (size_t)(kt)*64 + (ksl)*32,                                        \
                smB + (buf)*32768 + (ksl)*16384 + tid * 16);                            \
    GLOAD_LDS16(Bg + (size_t)128 * K + (kt)*64 + (ksl)*32,                              \
                smB + (buf)*32768 + (ksl)*16384 + 8192 + tid * 16);                     \
  } while (0)

  const int physB = lg ^ ((lrow >> 1) & 3);  // B read slot (lrow-only -> hoisted)

  const f32x4 fz = {0.f, 0.f, 0.f, 0.f};
  f32x4 acc[8][4];
#pragma unroll
  for (int m = 0; m < 8; m++)
#pragma unroll
    for (int n = 0; n < 4; n++) acc[m][n] = fz;

  const int NT = K >> 6;
  // prologue: tile 0 -> buf 0 (order: A-lo, A-hi, B-k0, B-k1)
  STAGE_A8(0, 0, 0);
  STAGE_A8(0, 1, 0);
  STAGE_B8(0, 0, 0);
  STAGE_B8(0, 1, 0);

  for (int kt = 0; kt < NT; ++kt) {
    const int buf = kt & 1, nb = buf ^ 1, nxt = kt + 1;
    const bool pf = nxt < NT;
    const char* Ab = smA + buf * 32768 + wm * 16384;
    const char* Bb = smB + buf * 32768;

    // pre-ph0: A-lo,A-hi,B-k0 of this tile ready; B-k1 (2 loads) may stay in flight
    asm volatile("s_waitcnt vmcnt(2)" ::: "memory");
    __builtin_amdgcn_s_barrier();

    bf16x8 a0[4], a1[4], b0[4], b1[4];
    // ---- phase 0: m0..3 x kk0 ----
#pragma unroll
    for (int i = 0; i < 4; i++) {
      const int r = i * 16 + lrow;
      a0[i] = *(const bf16x8*)(Ab + r * 128 + ((lg) ^ (r & 7)) * 16);
    }
#pragma unroll
    for (int i = 0; i < 4; i++) {
      const int r = wn * 64 + i * 16 + lrow;
      b0[i] = *(const bf16x8*)(Bb + r * 64 + physB * 16);
    }
    if (pf) STAGE_A8(nb, 0, nxt);
    __builtin_amdgcn_s_setprio(1);
#pragma unroll
    for (int m = 0; m < 4; m++)
#pragma unroll
      for (int n = 0; n < 4; n++)
        acc[m][n] = __builtin_amdgcn_mfma_f32_16x16x32_bf16(a0[m], b0[n], acc[m][n], 0, 0, 0);
    __builtin_amdgcn_s_setprio(0);
    // ---- phase 1: m4..7 x kk0 ----
#pragma unroll
    for (int i = 0; i < 4; i++) {
      const int r = (4 + i) * 16 + lrow;
      a1[i] = *(const bf16x8*)(Ab + r * 128 + ((lg) ^ (r & 7)) * 16);
    }
    if (pf) STAGE_A8(nb, 1, nxt);
    __builtin_amdgcn_s_setprio(1);
#pragma unroll
    for (int m = 0; m < 4; m++)
#pragma unroll
      for (int n = 0; n < 4; n++)
        acc[4 + m][n] = __builtin_amdgcn_mfma_f32_16x16x32_bf16(a1[m], b0[n], acc[4 + m][n], 0, 0, 0);
    __builtin_amdgcn_s_setprio(0);

    // pre-ph2: B-k1 of this tile ready; next tile's A (4 loads) may stay in flight
    if (pf) {
      asm volatile("s_waitcnt vmcnt(4)" ::: "memory");
    } else {
      asm volatile("s_waitcnt vmcnt(0)" ::: "memory");
    }
    __builtin_amdgcn_s_barrier();

    // ---- phase 2: m0..3 x kk1 ----
#pragma unroll
    for (int i = 0; i < 4; i++) {
      const int r = i * 16 + lrow;
      a0[i] = *(const bf16x8*)(Ab + r * 128 + ((4 + lg) ^ (r & 7)) * 16);
    }
#pragma unroll
    for (int i = 0; i < 4; i++) {
      const int r = wn * 64 + i * 16 + lrow;
      b1[i] = *(const bf16x8*)(Bb + 16384 + r * 64 + physB * 16);
    }
    if (pf) STAGE_B8(nb, 0, nxt);
    __builtin_amdgcn_s_setprio(1);
#pragma unroll
    for (int m = 0; m < 4; m++)
#pragma unroll
      for (int n = 0; n < 4; n++)
        acc[m][n] = __builtin_amdgcn_mfma_f32_16x16x32_bf16(a0[m], b1[n], acc[m][n], 0, 0, 0);
    __builtin_amdgcn_s_setprio(0);
    // ---- phase 3: m4..7 x kk1 ----
#pragma unroll
    for (int i = 0; i < 4; i++) {
      const int r = (4 + i) * 16 + lrow;
      a1[i] = *(const bf16x8*)(Ab + r * 128 + ((4 + lg) ^ (r & 7)) * 16);
    }
    if (pf) STAGE_B8(nb, 1, nxt);
    __builtin_amdgcn_s_setprio(1);
#pragma unroll
    for (int m = 0; m < 4; m++)
#pragma unroll
      for (int n = 0; n < 4; n++)
        acc[4 + m][n] = __builtin_amdgcn_mfma_f32_16x16x32_bf16(a1[m], b1[n], acc[4 + m][n], 0, 0, 0);
    __builtin_amdgcn_s_setprio(0);
  }

  // epilogue
#pragma unroll
  for (int n = 0; n < 4; n++) {
    const int col = colBase + wn * 64 + n * 16 + lrow;
    const float bval = bias[col];
#pragma unroll
    for (int m = 0; m < 8; m++) {
      const int row0 = rowBase + wm * 128 + m * 16 + lg * 4;
      if (EPI == 3 && col >= 2048) {
        const int c2 = col - 2048;
        const int hh = c2 >> 6, dd = c2 & 63;
        const int bat = row0 >> 11, tok0 = row0 & 2047;
        u16x4 pk;
#pragma unroll
        for (int r = 0; r < 4; r++) pk[r] = f2bf(acc[m][n][r] + bval);
        *(u16x4*)(vt + ((size_t)(bat * 16 + hh) * 64 + dd) * 2048 + tok0) = pk;
      } else if (EPI == 3) {
#pragma unroll
        for (int r = 0; r < 4; r++)
          ((u16*)out)[(size_t)(row0 + r) * 2048 + col] = f2bf(acc[m][n][r] + bval);
      } else if (EPI == 2) {
#pragma unroll
        for (int r = 0; r < 4; r++)
          ((u16*)out)[(size_t)(row0 + r) * N + col] = f2bf(gelu_f(acc[m][n][r] + bval));
      } else {
#pragma unroll
        for (int r = 0; r < 4; r++)
          ((u16*)out)[(size_t)(row0 + r) * N + col] = f2bf(acc[m][n][r] + bval);
      }
    }
  }
#undef STAGE_A8
#undef STAGE_B8
}

// ---------------- causal flash attention v3 (unchanged from R3) ----------------
__global__ __launch_bounds__(256, 2) void k_attention(
    const u16* __restrict__ qk, const u16* __restrict__ VT, u16* __restrict__ out) {
  const int S = 2048, E2 = 2048;
  const int bid = blockIdx.x;
  const int pid = bid >> 5;
  const int bh = bid & 31;
  const int bat = bh >> 4, h = bh & 15;
  const u16* base = qk + (size_t)bat * S * E2;
  const u16* kbase = base + 1024 + h * 64;
  const u16* vbase = VT + (size_t)bh * 64 * S;  // [d][tok]
  const int tid = threadIdx.x, w = tid >> 6, l = tid & 63;
  const int lrow = l & 15, lg = l >> 4;
  __shared__ u16 Ks[2][64 * 64];
  __shared__ u16 Vs[2][64 * 64];
  __shared__ u16 Pl[4][16 * 64];
  u16* Plw = Pl[w];
  const int srow = tid >> 3, sslot = tid & 7;
  const int gs = sslot ^ (srow & 7);
  const float sc = 0.125f * LOG2E;
  const f32x4 fz = {0.f, 0.f, 0.f, 0.f};

  auto STAGE = [&](int bufi, int kb) {
#pragma unroll
    for (int round = 0; round < 2; round++) {
      const int r = srow + 32 * round;
      GLOAD_LDS16(kbase + (size_t)(kb + r) * E2 + gs * 8, (char*)Ks[bufi] + round * 4096 + tid * 16);
      GLOAD_LDS16(vbase + (size_t)r * S + kb + gs * 8, (char*)Vs[bufi] + round * 4096 + tid * 16);
    }
  };

  for (int pass = 0; pass < 2; ++pass) {
    const int qt = pass ? (31 - pid) : pid;
    const int qrow0 = qt * 64 + w * 16;
    const int nkt = qt + 1;

    bf16x8 qfrag[2];
#pragma unroll
    for (int kc = 0; kc < 2; kc++)
      qfrag[kc] = *(const bf16x8*)(base + (size_t)(qrow0 + lrow) * E2 + h * 64 + kc * 32 + lg * 8);

    f32x4 o[4];
    float mrow[4], lsum[4];
#pragma unroll
    for (int r = 0; r < 4; r++) { mrow[r] = -1e30f; lsum[r] = 0.f; }
#pragma unroll
    for (int df = 0; df < 4; df++) o[df] = fz;

    STAGE(0, 0);
    __syncthreads();

    for (int kt = 0; kt < nkt; kt++) {
      const int cur = kt & 1;
      const int kb = kt * 64;
      if (kt + 1 < nkt) STAGE(cur ^ 1, kb + 64);
      const u16* Kc = Ks[cur];
      const u16* Vc = Vs[cur];

      f32x4 sv[4];
#pragma unroll
      for (int kf = 0; kf < 4; kf++) sv[kf] = fz;
#pragma unroll
      for (int kc = 0; kc < 2; kc++) {
        bf16x8 kfr[4];
#pragma unroll
        for (int kf = 0; kf < 4; kf++) {
          const int rk = kf * 16 + lrow;
          kfr[kf] = *(const bf16x8*)(Kc + rk * 64 + ((kc * 4 + lg) ^ (rk & 7)) * 8);
        }
#pragma unroll
        for (int kf = 0; kf < 4; kf++)
          sv[kf] = __builtin_amdgcn_mfma_f32_16x16x32_bf16(qfrag[kc], kfr[kf], sv[kf], 0, 0, 0);
      }
#pragma unroll
      for (int kf = 0; kf < 4; kf++)
#pragma unroll
        for (int r = 0; r < 4; r++) sv[kf][r] *= sc;
      if (kt == nkt - 1) {
#pragma unroll
        for (int kf = 0; kf < 4; kf++) {
          const int kg = kb + kf * 16 + lrow;
#pragma unroll
          for (int r = 0; r < 4; r++) {
            const int qg = qrow0 + lg * 4 + r;
            if (kg > qg) sv[kf][r] = -1e30f;
          }
        }
      }
#pragma unroll
      for (int r = 0; r < 4; r++) {
        float mx = fmaxf(fmaxf(sv[0][r], sv[1][r]), fmaxf(sv[2][r], sv[3][r]));
#pragma unroll
        for (int msk = 1; msk < 16; msk <<= 1) mx = fmaxf(mx, __shfl_xor(mx, msk));
        const float mnew = fmaxf(mrow[r], mx);
        const float corr = exp2f(mrow[r] - mnew);
        mrow[r] = mnew;
        lsum[r] *= corr;
#pragma unroll
        for (int df = 0; df < 4; df++) o[df][r] *= corr;
        float rsv = 0.f;
#pragma unroll
        for (int kf = 0; kf < 4; kf++) {
          const float p = exp2f(sv[kf][r] - mnew);
          sv[kf][r] = p;
          rsv += p;
        }
#pragma unroll
        for (int msk = 1; msk < 16; msk <<= 1) rsv += __shfl_xor(rsv, msk);
        lsum[r] += rsv;
      }
#pragma unroll
      for (int kf = 0; kf < 4; kf++)
#pragma unroll
        for (int r = 0; r < 4; r++) {
          const int q = lg * 4 + r;
          *(u16*)((char*)Plw + q * 128 + ((kf * 32 + lrow * 2) ^ ((q & 7) << 4))) = f2bf(sv[kf][r]);
        }
#pragma unroll
      for (int kc = 0; kc < 2; kc++) {
        const bf16x8 pa =
            *(const bf16x8*)((const char*)Plw + lrow * 128 + (((kc * 4 + lg) ^ (lrow & 7)) << 4));
        bf16x8 vb[4];
#pragma unroll
        for (int df = 0; df < 4; df++) {
          const int rd = df * 16 + lrow;
          vb[df] = *(const bf16x8*)(Vc + rd * 64 + ((kc * 4 + lg) ^ (rd & 7)) * 8);
        }
#pragma unroll
        for (int df = 0; df < 4; df++)
          o[df] = __builtin_amdgcn_mfma_f32_16x16x32_bf16(pa, vb[df], o[df], 0, 0, 0);
      }
      __syncthreads();
    }
#pragma unroll
    for (int r = 0; r < 4; r++) {
      const float inv = 1.0f / lsum[r];
      const int qg = qrow0 + lg * 4 + r;
#pragma unroll
      for (int df = 0; df < 4; df++) {
        const int col = h * 64 + df * 16 + lrow;
        out[(size_t)(bat * S + qg) * 1024 + col] = f2bf(o[df][r] * inv);
      }
    }
  }
}

// ---------------- host launch ----------------
extern "C" void kernel_launch(void* const* d_in, const int* in_sizes, int n_in,
                              void* d_out, int out_size, void* d_ws, size_t ws_size,
                              hipStream_t stream) {
  (void)in_sizes; (void)n_in; (void)out_size; (void)ws_size;
  const float* x      = (const float*)d_in[0];
  const float* ln1_g  = (const float*)d_in[1];
  const float* ln1_b  = (const float*)d_in[2];
  const float* W_attn = (const float*)d_in[3];
  const float* b_attn = (const float*)d_in[4];
  const float* W_proj = (const float*)d_in[5];
  const float* b_proj = (const float*)d_in[6];
  const float* ln2_g  = (const float*)d_in[7];
  const float* ln2_b  = (const float*)d_in[8];
  const float* W_fc   = (const float*)d_in[9];
  const float* b_fc   = (const float*)d_in[10];
  const float* W_mlp  = (const float*)d_in[11];
  const float* b_mlp  = (const float*)d_in[12];

  const int M = 4096;  // B*S = 2*2048
  char* ws = (char*)d_ws;
  size_t off = 0;
  auto alloc = [&](size_t bytes) {
    void* p = ws + off;
    off += (bytes + 255) & ~(size_t)255;
    return p;
  };
  u16* WattnT = (u16*)alloc((size_t)3072 * 1024 * 2);
  u16* WprojT = (u16*)alloc((size_t)1024 * 1024 * 2);
  u16* WfcT   = (u16*)alloc((size_t)4096 * 1024 * 2);
  u16* WmlpT  = (u16*)alloc((size_t)1024 * 4096 * 2);
  u16* x1     = (u16*)alloc((size_t)M * 1024 * 2);
  u16* qkb    = (u16*)alloc((size_t)M * 2048 * 2);        // Q|K only
  u16* VT     = (u16*)alloc((size_t)32 * 64 * 2048 * 2);  // [b*h][d][tok]
  u16* attno  = (u16*)alloc((size_t)M * 1024 * 2);
  float* x2   = (float*)alloc((size_t)M * 1024 * 4);
  u16* x3     = (u16*)alloc((size_t)M * 1024 * 2);
  u16* hbuf   = (u16*)alloc((size_t)M * 4096 * 2);

  // opt-in to 128KB dynamic LDS for the 8-phase kernels (idempotent, host-side)
  static bool attr_done = false;
  if (!attr_done) {
    hipFuncSetAttribute((const void*)k_gemm8<3>, hipFuncAttributeMaxDynamicSharedMemorySize, 131072);
    hipFuncSetAttribute((const void*)k_gemm8<2>, hipFuncAttributeMaxDynamicSharedMemorySize, 131072);
    attr_done = true;
  }

  const dim3 blk(256);
  k_transpose_bf16<<<dim3(3072 / 32, 1024 / 32), blk, 0, stream>>>(W_attn, WattnT, 1024, 3072);
  k_transpose_bf16<<<dim3(1024 / 32, 1024 / 32), blk, 0, stream>>>(W_proj, WprojT, 1024, 1024);
  k_transpose_bf16<<<dim3(4096 / 32, 1024 / 32), blk, 0, stream>>>(W_fc, WfcT, 1024, 4096);
  k_transpose_bf16<<<dim3(1024 / 32, 4096 / 32), blk, 0, stream>>>(W_mlp, WmlpT, 4096, 1024);

  k_layernorm_bf16<<<M, blk, 0, stream>>>(x, ln1_g, ln1_b, x1);
  // QKV: 256^2 8-phase, grid 12x16=192 (%8==0), EPI3 split epilogue
  k_gemm8<3><<<dim3((3072 / 256) * (M / 256)), dim3(512), 131072, stream>>>(
      x1, WattnT, b_attn, qkb, VT, M, 3072, 1024, 3072 / 256);
  k_attention<<<dim3(512), blk, 0, stream>>>(qkb, VT, attno);
  k_gemm_bt<1><<<dim3(1024 / 128, M / 128), blk, 0, stream>>>(attno, WprojT, b_proj, x1, x2, nullptr, M, 1024, 1024);
  k_layernorm_bf16<<<M, blk, 0, stream>>>(x2, ln2_g, ln2_b, x3);
  // FC: 256^2 8-phase, grid 16x16=256, EPI2 gelu
  k_gemm8<2><<<dim3((4096 / 256) * (M / 256)), dim3(512), 131072, stream>>>(
      x3, WfcT, b_fc, hbuf, nullptr, M, 4096, 1024, 4096 / 256);
  k_gemm_bt<1><<<dim3(1024 / 128, M / 128), blk, 0, stream>>>(hbuf, WmlpT, b_mlp, x3, d_out, nullptr, M, 1024, 4096);
}

// Round 5
// 272.852 us; speedup vs baseline: 1.5400x; 1.0636x over previous
//
#include <hip/hip_runtime.h>
#include <cstdint>

typedef __attribute__((ext_vector_type(8))) short bf16x8;
typedef __attribute__((ext_vector_type(4))) float f32x4;
typedef __attribute__((ext_vector_type(4))) unsigned short u16x4;
typedef unsigned short u16;

#define LOG2E 1.44269504088896340736f

__device__ __forceinline__ u16 f2bf(float f) {
  unsigned u = __builtin_bit_cast(unsigned, f);
  u += 0x7FFFu + ((u >> 16) & 1u);
  return (u16)(u >> 16);
}
__device__ __forceinline__ float bf2f(u16 h) {
  return __builtin_bit_cast(float, ((unsigned)h) << 16);
}

#define GLOAD_LDS16(g, l)                                                              \
  __builtin_amdgcn_global_load_lds((const __attribute__((address_space(1))) void*)(g), \
                                   (__attribute__((address_space(3))) void*)(l), 16, 0, 0)

// ---------------- weight transpose f32[K][N] -> bf16[N][K] ----------------
__global__ __launch_bounds__(256) void k_transpose_bf16(
    const float* __restrict__ W, u16* __restrict__ Wt, int K, int N) {
  __shared__ float tile[32][33];
  const int tid = threadIdx.x;
  const int tx = tid & 31, ty = tid >> 5;
  const int n0 = blockIdx.x * 32, k0 = blockIdx.y * 32;
#pragma unroll
  for (int i = 0; i < 32; i += 8)
    tile[ty + i][tx] = W[(size_t)(k0 + ty + i) * N + n0 + tx];
  __syncthreads();
#pragma unroll
  for (int i = 0; i < 32; i += 8)
    Wt[(size_t)(n0 + ty + i) * K + k0 + tx] = f2bf(tile[tx][ty + i]);
}

// ---------------- LayerNorm f32[row][1024] -> bf16 ----------------
__global__ __launch_bounds__(256) void k_layernorm_bf16(
    const float* __restrict__ x, const float* __restrict__ g,
    const float* __restrict__ b, u16* __restrict__ y) {
  const int row = blockIdx.x, tid = threadIdx.x;
  const float4 v = ((const float4*)(x + (size_t)row * 1024))[tid];
  float s = v.x + v.y + v.z + v.w;
#pragma unroll
  for (int m = 1; m < 64; m <<= 1) s += __shfl_xor(s, m);
  __shared__ float ps[8];
  if ((tid & 63) == 0) ps[tid >> 6] = s;
  __syncthreads();
  const float mean = (ps[0] + ps[1] + ps[2] + ps[3]) * (1.0f / 1024.0f);
  const float d0 = v.x - mean, d1 = v.y - mean, d2 = v.z - mean, d3 = v.w - mean;
  float s2 = d0 * d0 + d1 * d1 + d2 * d2 + d3 * d3;
#pragma unroll
  for (int m = 1; m < 64; m <<= 1) s2 += __shfl_xor(s2, m);
  if ((tid & 63) == 0) ps[4 + (tid >> 6)] = s2;
  __syncthreads();
  const float var = (ps[4] + ps[5] + ps[6] + ps[7]) * (1.0f / 1024.0f);
  const float rstd = rsqrtf(var + 1e-5f);
  const float4 gv = ((const float4*)g)[tid];
  const float4 bv = ((const float4*)b)[tid];
  u16x4 o;
  o[0] = f2bf(d0 * rstd * gv.x + bv.x);
  o[1] = f2bf(d1 * rstd * gv.y + bv.y);
  o[2] = f2bf(d2 * rstd * gv.z + bv.z);
  o[3] = f2bf(d3 * rstd * gv.w + bv.w);
  *(u16x4*)(y + (size_t)row * 1024 + tid * 4) = o;
}

__device__ __forceinline__ float gelu_f(float x) {
  const float u = 0.7978845608028654f * (x + 0.044715f * x * x * x);
  const float e = exp2f(u * 2.8853900817779268f);  // e^{2u}
  const float t = 1.0f - 2.0f / (e + 1.0f);        // tanh(u)
  return 0.5f * x * (1.0f + t);
}

// ---------------- 128x128 GEMM, double-buffered (T3-minimal) ----------------
// EPI 1: f32 out + bf16 residual
template <int EPI>
__global__ __launch_bounds__(256, 2) void k_gemm_bt(
    const u16* __restrict__ A, const u16* __restrict__ Bt,
    const float* __restrict__ bias, const u16* __restrict__ resid,
    void* __restrict__ out, u16* __restrict__ vt, int M, int N, int K) {
  __shared__ u16 As[2][128 * 64];
  __shared__ u16 Bs[2][128 * 64];
  const int tid = threadIdx.x;
  const int rowBase = blockIdx.y * 128, colBase = blockIdx.x * 128;
  const int w = tid >> 6, l = tid & 63;
  const int wm = w >> 1, wn = w & 1;
  const int lrow = l & 15, lg = l >> 4;
  const int srow = tid >> 3, sslot = tid & 7;

  const f32x4 fz = {0.f, 0.f, 0.f, 0.f};
  f32x4 acc[4][4];
#pragma unroll
  for (int m = 0; m < 4; m++)
#pragma unroll
    for (int n = 0; n < 4; n++) acc[m][n] = fz;

  const int NT = K >> 6;
  auto STAGE = [&](int b, int kt) {
#pragma unroll
    for (int i = 0; i < 4; i++) {
      const int r = srow + 32 * i;
      const int gs = sslot ^ (r & 7);  // inverse-swizzled source, linear LDS dest
      GLOAD_LDS16(A + (size_t)(rowBase + r) * K + kt * 64 + gs * 8,
                  (char*)As[b] + i * 4096 + tid * 16);
      GLOAD_LDS16(Bt + (size_t)(colBase + r) * K + kt * 64 + gs * 8,
                  (char*)Bs[b] + i * 4096 + tid * 16);
    }
  };

  STAGE(0, 0);
  for (int kt = 0; kt < NT; ++kt) {
    const int buf = kt & 1;
    if (kt + 1 < NT) {
      STAGE(buf ^ 1, kt + 1);  // issue next tile's loads BEFORE waiting on current
      asm volatile("s_waitcnt vmcnt(8)" ::: "memory");  // current tile done, next in flight
    } else {
      asm volatile("s_waitcnt vmcnt(0)" ::: "memory");
    }
    __builtin_amdgcn_s_barrier();
    const char* Ab = (const char*)As[buf];
    const char* Bb = (const char*)Bs[buf];
#pragma unroll
    for (int kc = 0; kc < 2; kc++) {
      bf16x8 av[4], bv[4];
#pragma unroll
      for (int m = 0; m < 4; m++) {
        const int r = wm * 64 + m * 16 + lrow;
        const int sl = (kc * 4 + lg) ^ (r & 7);
        av[m] = *(const bf16x8*)(Ab + r * 128 + sl * 16);
      }
#pragma unroll
      for (int n = 0; n < 4; n++) {
        const int r = wn * 64 + n * 16 + lrow;
        const int sl = (kc * 4 + lg) ^ (r & 7);
        bv[n] = *(const bf16x8*)(Bb + r * 128 + sl * 16);
      }
#pragma unroll
      for (int m = 0; m < 4; m++)
#pragma unroll
        for (int n = 0; n < 4; n++)
          acc[m][n] = __builtin_amdgcn_mfma_f32_16x16x32_bf16(av[m], bv[n], acc[m][n], 0, 0, 0);
    }
    __builtin_amdgcn_s_barrier();  // all waves done reading buf before next STAGE overwrites it
  }
#pragma unroll
  for (int n = 0; n < 4; n++) {
    const int col = colBase + wn * 64 + n * 16 + lrow;
    const float bval = bias[col];
#pragma unroll
    for (int m = 0; m < 4; m++) {
      const int row0 = rowBase + wm * 64 + m * 16 + lg * 4;
#pragma unroll
      for (int r = 0; r < 4; r++) {
        const size_t idx = (size_t)(row0 + r) * N + col;
        float v = acc[m][n][r] + bval;
        if (EPI == 0) {
          ((u16*)out)[idx] = f2bf(v);
        } else if (EPI == 2) {
          ((u16*)out)[idx] = f2bf(gelu_f(v));
        } else {
          v += bf2f(resid[idx]);
          ((float*)out)[idx] = v;
        }
      }
    }
  }
}

// ---------------- 256x256 8-phase GEMM (T2+T3+T4+T5), 512 thr, 128KB LDS ----------
// EPI 2: bf16 out + gelu
// EPI 3: qkv split epilogue (Q|K row-stride 2048; V transposed per head into vt)
// Stage-early schedule: all 4 units of tile kt+1 issued in ph0/ph1 of tile kt.
// Waits: vmcnt(2) pre-ph0 (A+B-k0 ready, B-k1 in flight; >=3-phase cover),
//        vmcnt(8) pre-ph2 (B-k1 ready, 8 next-tile loads in flight).
template <int EPI>
__global__ __launch_bounds__(512, 1) void k_gemm8(
    const u16* __restrict__ A, const u16* __restrict__ Bt,
    const float* __restrict__ bias, void* __restrict__ out,
    u16* __restrict__ vt, int M, int N, int K, int nbx) {
  extern __shared__ char sm[];
  char* smA = sm;
  char* smB = sm + 65536;
  const int tid = threadIdx.x;
  // bijective XCD swizzle (gridDim.x % 8 == 0 guaranteed by caller)
  const int q8 = gridDim.x >> 3;
  const int wg = (blockIdx.x & 7) * q8 + (blockIdx.x >> 3);
  const int bx = wg % nbx, by = wg / nbx;
  const int rowBase = by * 256, colBase = bx * 256;
  const int w = tid >> 6, l = tid & 63;
  const int wm = w >> 2, wn = w & 3;
  const int lrow = l & 15, lg = l >> 4;

  // staging address constants
  const int sArow = tid >> 3;
  const int gsA = (tid & 7) ^ (sArow & 7);
  const int sBrow = tid >> 2;
  const int gsB = (tid & 3) ^ ((tid >> 3) & 3);
  const u16* Ag = A + (size_t)(rowBase + sArow) * K + gsA * 8;
  const u16* Bg = Bt + (size_t)(colBase + sBrow) * K + gsB * 8;

#define STAGE_A8(buf, half, kt)                                                         \
  do {                                                                                  \
    GLOAD_LDS16(Ag + ((size_t)(half)*128) * K + (kt)*64,                                \
                smA + (buf)*32768 + (half)*16384 + tid * 16);                           \
    GLOAD_LDS16(Ag + ((size_t)(half)*128 + 64) * K + (kt)*64,                           \
                smA + (buf)*32768 + (half)*16384 + 8192 + tid * 16);                    \
  } while (0)
#define STAGE_B8(buf, ksl, kt)                                                          \
  do {                                                                                  \
    GLOAD_LDS16(Bg + (size_t)(kt)*64 + (ksl)*32,                                        \
                smB + (buf)*32768 + (ksl)*16384 + tid * 16);                            \
    GLOAD_LDS16(Bg + (size_t)128 * K + (kt)*64 + (ksl)*32,                              \
                smB + (buf)*32768 + (ksl)*16384 + 8192 + tid * 16);                     \
  } while (0)

  const int physB = lg ^ ((lrow >> 1) & 3);  // B read slot (lrow-only -> hoisted)

  const f32x4 fz = {0.f, 0.f, 0.f, 0.f};
  f32x4 acc[8][4];
#pragma unroll
  for (int m = 0; m < 8; m++)
#pragma unroll
    for (int n = 0; n < 4; n++) acc[m][n] = fz;

  const int NT = K >> 6;
  // prologue: tile 0 -> buf 0 (order: A-lo, A-hi, B-k0, B-k1)
  STAGE_A8(0, 0, 0);
  STAGE_A8(0, 1, 0);
  STAGE_B8(0, 0, 0);
  STAGE_B8(0, 1, 0);

  for (int kt = 0; kt < NT; ++kt) {
    const int buf = kt & 1, nb = buf ^ 1, nxt = kt + 1;
    const bool pf = nxt < NT;
    const char* Ab = smA + buf * 32768 + wm * 16384;
    const char* Bb = smB + buf * 32768;

    // pre-ph0: A-lo,A-hi,B-k0 of this tile ready; B-k1 (2 loads) may stay in flight
    asm volatile("s_waitcnt vmcnt(2)" ::: "memory");
    __builtin_amdgcn_s_barrier();

    bf16x8 a0[4], a1[4], b0[4], b1[4];
    // ---- phase 0: m0..3 x kk0 ; issue next-tile A (both halves) ----
#pragma unroll
    for (int i = 0; i < 4; i++) {
      const int r = i * 16 + lrow;
      a0[i] = *(const bf16x8*)(Ab + r * 128 + ((lg) ^ (r & 7)) * 16);
    }
#pragma unroll
    for (int i = 0; i < 4; i++) {
      const int r = wn * 64 + i * 16 + lrow;
      b0[i] = *(const bf16x8*)(Bb + r * 64 + physB * 16);
    }
    if (pf) {
      STAGE_A8(nb, 0, nxt);
      STAGE_A8(nb, 1, nxt);
    }
    __builtin_amdgcn_s_setprio(1);
#pragma unroll
    for (int m = 0; m < 4; m++)
#pragma unroll
      for (int n = 0; n < 4; n++)
        acc[m][n] = __builtin_amdgcn_mfma_f32_16x16x32_bf16(a0[m], b0[n], acc[m][n], 0, 0, 0);
    __builtin_amdgcn_s_setprio(0);
    // ---- phase 1: m4..7 x kk0 ; issue next-tile B (both k-slices) ----
#pragma unroll
    for (int i = 0; i < 4; i++) {
      const int r = (4 + i) * 16 + lrow;
      a1[i] = *(const bf16x8*)(Ab + r * 128 + ((lg) ^ (r & 7)) * 16);
    }
    if (pf) {
      STAGE_B8(nb, 0, nxt);
      STAGE_B8(nb, 1, nxt);
    }
    __builtin_amdgcn_s_setprio(1);
#pragma unroll
    for (int m = 0; m < 4; m++)
#pragma unroll
      for (int n = 0; n < 4; n++)
        acc[4 + m][n] = __builtin_amdgcn_mfma_f32_16x16x32_bf16(a1[m], b0[n], acc[4 + m][n], 0, 0, 0);
    __builtin_amdgcn_s_setprio(0);

    // pre-ph2: B-k1 of this tile ready; next tile's 8 loads may stay in flight
    if (pf) {
      asm volatile("s_waitcnt vmcnt(8)" ::: "memory");
    } else {
      asm volatile("s_waitcnt vmcnt(0)" ::: "memory");
    }
    __builtin_amdgcn_s_barrier();

    // ---- phase 2: m0..3 x kk1 ----
#pragma unroll
    for (int i = 0; i < 4; i++) {
      const int r = i * 16 + lrow;
      a0[i] = *(const bf16x8*)(Ab + r * 128 + ((4 + lg) ^ (r & 7)) * 16);
    }
#pragma unroll
    for (int i = 0; i < 4; i++) {
      const int r = wn * 64 + i * 16 + lrow;
      b1[i] = *(const bf16x8*)(Bb + 16384 + r * 64 + physB * 16);
    }
    __builtin_amdgcn_s_setprio(1);
#pragma unroll
    for (int m = 0; m < 4; m++)
#pragma unroll
      for (int n = 0; n < 4; n++)
        acc[m][n] = __builtin_amdgcn_mfma_f32_16x16x32_bf16(a0[m], b1[n], acc[m][n], 0, 0, 0);
    __builtin_amdgcn_s_setprio(0);
    // ---- phase 3: m4..7 x kk1 ----
#pragma unroll
    for (int i = 0; i < 4; i++) {
      const int r = (4 + i) * 16 + lrow;
      a1[i] = *(const bf16x8*)(Ab + r * 128 + ((4 + lg) ^ (r & 7)) * 16);
    }
    __builtin_amdgcn_s_setprio(1);
#pragma unroll
    for (int m = 0; m < 4; m++)
#pragma unroll
      for (int n = 0; n < 4; n++)
        acc[4 + m][n] = __builtin_amdgcn_mfma_f32_16x16x32_bf16(a1[m], b1[n], acc[4 + m][n], 0, 0, 0);
    __builtin_amdgcn_s_setprio(0);
  }

  // epilogue
#pragma unroll
  for (int n = 0; n < 4; n++) {
    const int col = colBase + wn * 64 + n * 16 + lrow;
    const float bval = bias[col];
#pragma unroll
    for (int m = 0; m < 8; m++) {
      const int row0 = rowBase + wm * 128 + m * 16 + lg * 4;
      if (EPI == 3 && col >= 2048) {
        const int c2 = col - 2048;
        const int hh = c2 >> 6, dd = c2 & 63;
        const int bat = row0 >> 11, tok0 = row0 & 2047;
        u16x4 pk;
#pragma unroll
        for (int r = 0; r < 4; r++) pk[r] = f2bf(acc[m][n][r] + bval);
        *(u16x4*)(vt + ((size_t)(bat * 16 + hh) * 64 + dd) * 2048 + tok0) = pk;
      } else if (EPI == 3) {
#pragma unroll
        for (int r = 0; r < 4; r++)
          ((u16*)out)[(size_t)(row0 + r) * 2048 + col] = f2bf(acc[m][n][r] + bval);
      } else if (EPI == 2) {
#pragma unroll
        for (int r = 0; r < 4; r++)
          ((u16*)out)[(size_t)(row0 + r) * N + col] = f2bf(gelu_f(acc[m][n][r] + bval));
      } else {
#pragma unroll
        for (int r = 0; r < 4; r++)
          ((u16*)out)[(size_t)(row0 + r) * N + col] = f2bf(acc[m][n][r] + bval);
      }
    }
  }
#undef STAGE_A8
#undef STAGE_B8
}

// ---------------- causal flash attention v3 (unchanged from R3) ----------------
__global__ __launch_bounds__(256, 2) void k_attention(
    const u16* __restrict__ qk, const u16* __restrict__ VT, u16* __restrict__ out) {
  const int S = 2048, E2 = 2048;
  const int bid = blockIdx.x;
  const int pid = bid >> 5;
  const int bh = bid & 31;
  const int bat = bh >> 4, h = bh & 15;
  const u16* base = qk + (size_t)bat * S * E2;
  const u16* kbase = base + 1024 + h * 64;
  const u16* vbase = VT + (size_t)bh * 64 * S;  // [d][tok]
  const int tid = threadIdx.x, w = tid >> 6, l = tid & 63;
  const int lrow = l & 15, lg = l >> 4;
  __shared__ u16 Ks[2][64 * 64];
  __shared__ u16 Vs[2][64 * 64];
  __shared__ u16 Pl[4][16 * 64];
  u16* Plw = Pl[w];
  const int srow = tid >> 3, sslot = tid & 7;
  const int gs = sslot ^ (srow & 7);
  const float sc = 0.125f * LOG2E;
  const f32x4 fz = {0.f, 0.f, 0.f, 0.f};

  auto STAGE = [&](int bufi, int kb) {
#pragma unroll
    for (int round = 0; round < 2; round++) {
      const int r = srow + 32 * round;
      GLOAD_LDS16(kbase + (size_t)(kb + r) * E2 + gs * 8, (char*)Ks[bufi] + round * 4096 + tid * 16);
      GLOAD_LDS16(vbase + (size_t)r * S + kb + gs * 8, (char*)Vs[bufi] + round * 4096 + tid * 16);
    }
  };

  for (int pass = 0; pass < 2; ++pass) {
    const int qt = pass ? (31 - pid) : pid;
    const int qrow0 = qt * 64 + w * 16;
    const int nkt = qt + 1;

    bf16x8 qfrag[2];
#pragma unroll
    for (int kc = 0; kc < 2; kc++)
      qfrag[kc] = *(const bf16x8*)(base + (size_t)(qrow0 + lrow) * E2 + h * 64 + kc * 32 + lg * 8);

    f32x4 o[4];
    float mrow[4], lsum[4];
#pragma unroll
    for (int r = 0; r < 4; r++) { mrow[r] = -1e30f; lsum[r] = 0.f; }
#pragma unroll
    for (int df = 0; df < 4; df++) o[df] = fz;

    STAGE(0, 0);
    __syncthreads();

    for (int kt = 0; kt < nkt; kt++) {
      const int cur = kt & 1;
      const int kb = kt * 64;
      if (kt + 1 < nkt) STAGE(cur ^ 1, kb + 64);
      const u16* Kc = Ks[cur];
      const u16* Vc = Vs[cur];

      f32x4 sv[4];
#pragma unroll
      for (int kf = 0; kf < 4; kf++) sv[kf] = fz;
#pragma unroll
      for (int kc = 0; kc < 2; kc++) {
        bf16x8 kfr[4];
#pragma unroll
        for (int kf = 0; kf < 4; kf++) {
          const int rk = kf * 16 + lrow;
          kfr[kf] = *(const bf16x8*)(Kc + rk * 64 + ((kc * 4 + lg) ^ (rk & 7)) * 8);
        }
#pragma unroll
        for (int kf = 0; kf < 4; kf++)
          sv[kf] = __builtin_amdgcn_mfma_f32_16x16x32_bf16(qfrag[kc], kfr[kf], sv[kf], 0, 0, 0);
      }
#pragma unroll
      for (int kf = 0; kf < 4; kf++)
#pragma unroll
        for (int r = 0; r < 4; r++) sv[kf][r] *= sc;
      if (kt == nkt - 1) {
#pragma unroll
        for (int kf = 0; kf < 4; kf++) {
          const int kg = kb + kf * 16 + lrow;
#pragma unroll
          for (int r = 0; r < 4; r++) {
            const int qg = qrow0 + lg * 4 + r;
            if (kg > qg) sv[kf][r] = -1e30f;
          }
        }
      }
#pragma unroll
      for (int r = 0; r < 4; r++) {
        float mx = fmaxf(fmaxf(sv[0][r], sv[1][r]), fmaxf(sv[2][r], sv[3][r]));
#pragma unroll
        for (int msk = 1; msk < 16; msk <<= 1) mx = fmaxf(mx, __shfl_xor(mx, msk));
        const float mnew = fmaxf(mrow[r], mx);
        const float corr = exp2f(mrow[r] - mnew);
        mrow[r] = mnew;
        lsum[r] *= corr;
#pragma unroll
        for (int df = 0; df < 4; df++) o[df][r] *= corr;
        float rsv = 0.f;
#pragma unroll
        for (int kf = 0; kf < 4; kf++) {
          const float p = exp2f(sv[kf][r] - mnew);
          sv[kf][r] = p;
          rsv += p;
        }
#pragma unroll
        for (int msk = 1; msk < 16; msk <<= 1) rsv += __shfl_xor(rsv, msk);
        lsum[r] += rsv;
      }
#pragma unroll
      for (int kf = 0; kf < 4; kf++)
#pragma unroll
        for (int r = 0; r < 4; r++) {
          const int q = lg * 4 + r;
          *(u16*)((char*)Plw + q * 128 + ((kf * 32 + lrow * 2) ^ ((q & 7) << 4))) = f2bf(sv[kf][r]);
        }
#pragma unroll
      for (int kc = 0; kc < 2; kc++) {
        const bf16x8 pa =
            *(const bf16x8*)((const char*)Plw + lrow * 128 + (((kc * 4 + lg) ^ (lrow & 7)) << 4));
        bf16x8 vb[4];
#pragma unroll
        for (int df = 0; df < 4; df++) {
          const int rd = df * 16 + lrow;
          vb[df] = *(const bf16x8*)(Vc + rd * 64 + ((kc * 4 + lg) ^ (rd & 7)) * 8);
        }
#pragma unroll
        for (int df = 0; df < 4; df++)
          o[df] = __builtin_amdgcn_mfma_f32_16x16x32_bf16(pa, vb[df], o[df], 0, 0, 0);
      }
      __syncthreads();
    }
#pragma unroll
    for (int r = 0; r < 4; r++) {
      const float inv = 1.0f / lsum[r];
      const int qg = qrow0 + lg * 4 + r;
#pragma unroll
      for (int df = 0; df < 4; df++) {
        const int col = h * 64 + df * 16 + lrow;
        out[(size_t)(bat * S + qg) * 1024 + col] = f2bf(o[df][r] * inv);
      }
    }
  }
}

// ---------------- host launch ----------------
extern "C" void kernel_launch(void* const* d_in, const int* in_sizes, int n_in,
                              void* d_out, int out_size, void* d_ws, size_t ws_size,
                              hipStream_t stream) {
  (void)in_sizes; (void)n_in; (void)out_size; (void)ws_size;
  const float* x      = (const float*)d_in[0];
  const float* ln1_g  = (const float*)d_in[1];
  const float* ln1_b  = (const float*)d_in[2];
  const float* W_attn = (const float*)d_in[3];
  const float* b_attn = (const float*)d_in[4];
  const float* W_proj = (const float*)d_in[5];
  const float* b_proj = (const float*)d_in[6];
  const float* ln2_g  = (const float*)d_in[7];
  const float* ln2_b  = (const float*)d_in[8];
  const float* W_fc   = (const float*)d_in[9];
  const float* b_fc   = (const float*)d_in[10];
  const float* W_mlp  = (const float*)d_in[11];
  const float* b_mlp  = (const float*)d_in[12];

  const int M = 4096;  // B*S = 2*2048
  char* ws = (char*)d_ws;
  size_t off = 0;
  auto alloc = [&](size_t bytes) {
    void* p = ws + off;
    off += (bytes + 255) & ~(size_t)255;
    return p;
  };
  u16* WattnT = (u16*)alloc((size_t)3072 * 1024 * 2);
  u16* WprojT = (u16*)alloc((size_t)1024 * 1024 * 2);
  u16* WfcT   = (u16*)alloc((size_t)4096 * 1024 * 2);
  u16* WmlpT  = (u16*)alloc((size_t)1024 * 4096 * 2);
  u16* x1     = (u16*)alloc((size_t)M * 1024 * 2);
  u16* qkb    = (u16*)alloc((size_t)M * 2048 * 2);        // Q|K only
  u16* VT     = (u16*)alloc((size_t)32 * 64 * 2048 * 2);  // [b*h][d][tok]
  u16* attno  = (u16*)alloc((size_t)M * 1024 * 2);
  float* x2   = (float*)alloc((size_t)M * 1024 * 4);
  u16* x3     = (u16*)alloc((size_t)M * 1024 * 2);
  u16* hbuf   = (u16*)alloc((size_t)M * 4096 * 2);

  // opt-in to 128KB dynamic LDS for the 8-phase kernels (idempotent, host-side)
  static bool attr_done = false;
  if (!attr_done) {
    hipFuncSetAttribute((const void*)k_gemm8<3>, hipFuncAttributeMaxDynamicSharedMemorySize, 131072);
    hipFuncSetAttribute((const void*)k_gemm8<2>, hipFuncAttributeMaxDynamicSharedMemorySize, 131072);
    attr_done = true;
  }

  const dim3 blk(256);
  k_transpose_bf16<<<dim3(3072 / 32, 1024 / 32), blk, 0, stream>>>(W_attn, WattnT, 1024, 3072);
  k_transpose_bf16<<<dim3(1024 / 32, 1024 / 32), blk, 0, stream>>>(W_proj, WprojT, 1024, 1024);
  k_transpose_bf16<<<dim3(4096 / 32, 1024 / 32), blk, 0, stream>>>(W_fc, WfcT, 1024, 4096);
  k_transpose_bf16<<<dim3(1024 / 32, 4096 / 32), blk, 0, stream>>>(W_mlp, WmlpT, 4096, 1024);

  k_layernorm_bf16<<<M, blk, 0, stream>>>(x, ln1_g, ln1_b, x1);
  // QKV: 256^2 8-phase, grid 12x16=192 (%8==0), EPI3 split epilogue
  k_gemm8<3><<<dim3((3072 / 256) * (M / 256)), dim3(512), 131072, stream>>>(
      x1, WattnT, b_attn, qkb, VT, M, 3072, 1024, 3072 / 256);
  k_attention<<<dim3(512), blk, 0, stream>>>(qkb, VT, attno);
  k_gemm_bt<1><<<dim3(1024 / 128, M / 128), blk, 0, stream>>>(attno, WprojT, b_proj, x1, x2, nullptr, M, 1024, 1024);
  k_layernorm_bf16<<<M, blk, 0, stream>>>(x2, ln2_g, ln2_b, x3);
  // FC: 256^2 8-phase, grid 16x16=256, EPI2 gelu
  k_gemm8<2><<<dim3((4096 / 256) * (M / 256)), dim3(512), 131072, stream>>>(
      x3, WfcT, b_fc, hbuf, nullptr, M, 4096, 1024, 4096 / 256);
  k_gemm_bt<1><<<dim3(1024 / 128, M / 128), blk, 0, stream>>>(hbuf, WmlpT, b_mlp, x3, d_out, nullptr, M, 1024, 4096);
}